// Round 12
// baseline (297.713 us; speedup 1.0000x reference)
//
#include <hip/hip_runtime.h>
#include <hip/hip_bf16.h>

// GNN forward: pre-Linear -> GATConv(6 heads, self-loops, edge softmax) -> concat -> Linear
// - Aggregation identity: sum_e coef_e*(h[s]@Wg) = (sum_e coef_e*h[s])@Wg -> gather 128B bf16 rows
// - Per-edge softmax weights computed once in k_fill -> 32B f32 records {src, w0..w5, pad}
// - k_agg: readfirstlane scalar record loads, 8-edge unroll
// - Launch chain compacted: memset(counts|cursor) -> k_setup(+detect+transposes+watt+HIST)
//   -> k_pre -> k_attscan(att blocks + single-block scan) -> k_fill -> k_agg -> k_tail
//   (self-loop +1 folded into the scan: counts holds in-degree WITHOUT self loop)
// - k_tail: separate BsG/BsL LDS buffers -> 3 barriers/head instead of 4
// - NOTE(R6/R7 lesson): do NOT fuse a_src/a_dst into k_pre as extra MFMA columns (80-col B tile)
//   -> post-timing graph-replay divergence, mechanism unidentified. k_att stays separate.
// N=50000, E=800000 (+N self loops), CUR=512, HID=64, OUT=64, HEADS=6

#define NN    50000
#define EE    800000
#define E2T   850000
#define CURD  512
#define HIDD  64
#define FD    384        // HEADS*OUT
#define CATK  448        // HID + FD

typedef __attribute__((ext_vector_type(8))) short short8;
typedef __attribute__((ext_vector_type(4))) float f32x4;

static __device__ __forceinline__ float b2f(unsigned short u) {
    union { unsigned int i; float f; } x; x.i = ((unsigned int)u) << 16; return x.f;
}
static __device__ __forceinline__ unsigned short f2b(float f) {
    unsigned int x = __float_as_uint(f);
    unsigned int r = (x + 0x7fffu + ((x >> 16) & 1u)) >> 16;
    return (unsigned short)r;
}
static __device__ __forceinline__ unsigned int packbf(float a, float b) {
    return (unsigned int)f2b(a) | ((unsigned int)f2b(b) << 16);
}
static __device__ __forceinline__ float lrelu(float v, float a) { return v > 0.f ? v : a * v; }

// ---------------- k_setup: detect | 3 weight transposes | watt | HIST (fused) ----------------
#define B_DET2  0             // 1 block: global flag for k_fill
#define B_TRWP2 1             // 1..128:   Wt[c][k]=Wp[k][c]
#define B_TRWL2 129           // 129..240: Wlt[c][k]=Wl[k][c]
#define B_TRWG2 241           // 241..336: Wgt[h][c][k]=Wg[k][h*64+c]
#define B_WATT2 337           // 337..338: wsv/wdv
#define B_HIST2 339           // 339..3463: histogram (3125 blocks, per-block local detect)
#define B_TOT2  3464

__global__ void k_setup(const int* __restrict__ ei,
                        const float* __restrict__ Wp, const float* __restrict__ Wl,
                        const float* __restrict__ Wg,
                        const float* __restrict__ atts, const float* __restrict__ attd,
                        unsigned int* __restrict__ counts, unsigned int* __restrict__ flag,
                        unsigned short* __restrict__ Wt, unsigned short* __restrict__ Wlt,
                        unsigned short* __restrict__ Wgt,
                        float* __restrict__ wsv, float* __restrict__ wdv) {
    __shared__ unsigned int anyv;
    const int b = blockIdx.x, t = threadIdx.x;
    if (b >= B_HIST2) {                               // histogram w/ local int64 detect
        if (t == 0) anyv = 0u;
        __syncthreads();
        unsigned int v = 0;
        for (int i = t; i < 2048; i += 256) v |= (unsigned int)ei[2 * i + 1];
        atomicOr(&anyv, v);
        __syncthreads();
        const bool wide = (anyv == 0u);
        int e = (b - B_HIST2) * 256 + t;
        if (e < EE) {
            int d = wide ? ei[2 * (EE + e)] : ei[EE + e];
            atomicAdd(&counts[d], 1u);
        }
    } else if (b == B_DET2) {
        if (t == 0) anyv = 0u;
        __syncthreads();
        unsigned int v = 0;
        for (int i = t; i < 2048; i += 256) v |= (unsigned int)ei[2 * i + 1];
        atomicOr(&anyv, v);
        __syncthreads();
        if (t == 0) *flag = (anyv == 0u) ? 1u : 0u;   // 1 => int64 layout
    } else if (b < B_TRWL2) {
        int i = (b - B_TRWP2) * 256 + t;              // Wt[c][k]=Wp[k][c], K=512
        int c = i >> 9, k = i & 511;
        Wt[i] = f2b(Wp[k * 64 + c]);
    } else if (b < B_TRWG2) {
        int i = (b - B_TRWL2) * 256 + t;
        if (i < 64 * CATK) {
            int c = i / CATK, k = i - c * CATK;
            Wlt[i] = f2b(Wl[k * 64 + c]);
        }
    } else if (b < B_WATT2) {
        int i = (b - B_TRWG2) * 256 + t;
        int hd = i >> 12, rem = i & 4095, c = rem >> 6, k = rem & 63;
        Wgt[i] = f2b(Wg[k * FD + hd * 64 + c]);
    } else {
        int j = (b - B_WATT2) * 256 + t;              // 384 total
        if (j < 384) {
            int hd = j >> 6, k = j & 63;
            float s = 0.f, d = 0.f;
            for (int c = 0; c < 64; c++) {
                float w = Wg[k * FD + hd * 64 + c];
                s = fmaf(w, atts[hd * 64 + c], s);
                d = fmaf(w, attd[hd * 64 + c], d);
            }
            wsv[j] = s; wdv[j] = d;
        }
    }
}

// ---------------- K1: hb = bf16(x @ W_pre + b_pre)  (bf16 MFMA, register-direct A) ----------------
__global__ __launch_bounds__(256) void k_pre(const float* __restrict__ x,
                                             const unsigned short* __restrict__ Wt,
                                             const float* __restrict__ bp,
                                             unsigned short* __restrict__ hb) {
    __shared__ unsigned short Bs[64][72];
    const int t  = threadIdx.x;
    const int n0 = blockIdx.x * 64;
    const int w = t >> 6, l = t & 63;
    const int fr = l & 15, fq = l >> 4;
    const int ar = t >> 2, ac = (t & 3) * 16;
    int arow = n0 + w * 16 + fr; if (arow >= NN) arow = NN - 1;
    f32x4 acc[4];
    #pragma unroll
    for (int nb = 0; nb < 4; nb++) acc[nb] = (f32x4){0.f, 0.f, 0.f, 0.f};

    for (int kt = 0; kt < CURD; kt += 64) {
        const float4* xp0 = (const float4*)(x + (size_t)arow * CURD + kt + 0 * 32 + fq * 8);
        const float4* xp1 = (const float4*)(x + (size_t)arow * CURD + kt + 1 * 32 + fq * 8);
        float4 a00 = xp0[0], a01 = xp0[1];
        float4 a10 = xp1[0], a11 = xp1[1];
        const uint4* wp = (const uint4*)(Wt + (size_t)ar * CURD + kt + ac);
        uint4 b0 = wp[0], b1 = wp[1];
        __syncthreads();
        *(uint4*)&Bs[ar][ac]     = b0;
        *(uint4*)&Bs[ar][ac + 8] = b1;
        __syncthreads();
        unsigned int afw[2][4] = {
            {packbf(a00.x,a00.y), packbf(a00.z,a00.w), packbf(a01.x,a01.y), packbf(a01.z,a01.w)},
            {packbf(a10.x,a10.y), packbf(a10.z,a10.w), packbf(a11.x,a11.y), packbf(a11.z,a11.w)}};
        #pragma unroll
        for (int ks = 0; ks < 2; ks++) {
            short8 af;
            __builtin_memcpy(&af, &afw[ks][0], 16);
            #pragma unroll
            for (int nb = 0; nb < 4; nb++) {
                short8 bf = *(const short8*)&Bs[nb * 16 + fr][ks * 32 + fq * 8];
                acc[nb] = __builtin_amdgcn_mfma_f32_16x16x32_bf16(af, bf, acc[nb], 0, 0, 0);
            }
        }
    }
    #pragma unroll
    for (int nb = 0; nb < 4; nb++) {
        const int col = nb * 16 + fr;
        const float bias = bp[col];
        #pragma unroll
        for (int r = 0; r < 4; r++) {
            const int row = n0 + w * 16 + fq * 4 + r;
            if (row < NN) hb[(size_t)row * HIDD + col] = f2b(acc[nb][r] + bias);
        }
    }
}

// ---- k_attscan: blocks 0..12499 att (asrcP/adstP); block 12500 = whole exclusive scan ----
#define ATTB 12500

__global__ __launch_bounds__(256) void k_attscan(const unsigned short* __restrict__ hb,
                                                 const float* __restrict__ ws,
                                                 const float* __restrict__ wd,
                                                 const unsigned int* __restrict__ counts,
                                                 float* __restrict__ asrcP, float* __restrict__ adstP,
                                                 unsigned int* __restrict__ offsets) {
    const int b = blockIdx.x, t = threadIdx.x;
    if (b < ATTB) {
        const int n = b * 4 + (t >> 6);
        if (n >= NN) return;
        const int l = t & 63;
        const float v = b2f(hb[(size_t)n * HIDD + l]);
        float ps[6], pd[6];
        #pragma unroll
        for (int hd = 0; hd < 6; hd++) {
            ps[hd] = v * ws[hd * 64 + l];
            pd[hd] = v * wd[hd * 64 + l];
        }
        #pragma unroll
        for (int o = 32; o > 0; o >>= 1) {
            #pragma unroll
            for (int hd = 0; hd < 6; hd++) {
                ps[hd] += __shfl_xor(ps[hd], o, 64);
                pd[hd] += __shfl_xor(pd[hd], o, 64);
            }
        }
        if (l == 0) {
            #pragma unroll
            for (int hd = 0; hd < 6; hd++) {
                asrcP[(size_t)n * 8 + hd] = ps[hd];
                adstP[(size_t)n * 8 + hd] = pd[hd];
            }
        }
    } else {
        // single-block exclusive scan of (counts[i]+1) -> offsets[0..NN]
        __shared__ unsigned int sc[256];
        const int per = 196;                    // 256*196 = 50176 >= NN
        int s = t * per, epos = s + per; if (epos > NN) epos = NN; if (s > NN) s = NN;
        unsigned int sum = 0;
        for (int i = s; i < epos; i++) sum += counts[i] + 1u;   // +1 = self loop
        sc[t] = sum;
        __syncthreads();
        for (int o = 1; o < 256; o <<= 1) {
            unsigned int xv = (t >= o) ? sc[t - o] : 0u;
            __syncthreads();
            sc[t] += xv;
            __syncthreads();
        }
        unsigned int run = (t == 0) ? 0u : sc[t - 1];
        for (int i = s; i < epos; i++) { offsets[i] = run; run += counts[i] + 1u; }
        if (epos == NN && s < NN) offsets[NN] = run;
    }
}

// ---------------- CSR fill + per-edge weights: edata[2*pos..] = {src, 6 x f32 w, 0} ----------------
__global__ void k_fill(const int* __restrict__ ei, const unsigned int* __restrict__ flag,
                       const unsigned int* __restrict__ offsets, unsigned int* __restrict__ cursor,
                       const float* __restrict__ asrcP, const float* __restrict__ adstP,
                       uint4* __restrict__ edata) {
    int e = blockIdx.x * 256 + threadIdx.x;
    if (e >= E2T) return;
    const bool wide = (*flag != 0u);
    int s, d;
    if (e < EE) {
        s = wide ? ei[2 * e] : ei[e];
        d = wide ? ei[2 * (EE + e)] : ei[EE + e];
    } else { s = d = e - EE; }
    unsigned int pos = offsets[d] + atomicAdd(&cursor[d], 1u);
    const float4 s0 = *(const float4*)(asrcP + (size_t)s * 8);
    const float2 s1 = *(const float2*)(asrcP + (size_t)s * 8 + 4);
    const float4 d0 = *(const float4*)(adstP + (size_t)d * 8);
    const float2 d1 = *(const float2*)(adstP + (size_t)d * 8 + 4);
    const float as[6] = {s0.x, s0.y, s0.z, s0.w, s1.x, s1.y};
    const float ad[6] = {d0.x, d0.y, d0.z, d0.w, d1.x, d1.y};
    float wv[6];
    #pragma unroll
    for (int hd = 0; hd < 6; hd++) {
        float a = as[hd] + ad[hd];
        a = fmaxf(a, 0.2f * a);                 // leaky_relu 0.2
        wv[hd] = __expf(a);                     // shift skipped: alpha O(1), softmax shift-invariant
    }
    uint4 u0, u1;
    u0.x = (unsigned int)s;
    u0.y = __float_as_uint(wv[0]); u0.z = __float_as_uint(wv[1]); u0.w = __float_as_uint(wv[2]);
    u1.x = __float_as_uint(wv[3]); u1.y = __float_as_uint(wv[4]); u1.z = __float_as_uint(wv[5]);
    u1.w = 0u;
    edata[2 * (size_t)pos]     = u0;
    edata[2 * (size_t)pos + 1] = u1;
}

// ---------------- k_agg: scalar record loads (8-edge unroll) + coalesced row gather ----------------
#define W6(ua, ub, nm) \
    const float nm[6] = {__uint_as_float(ua.y), __uint_as_float(ua.z), __uint_as_float(ua.w), \
                         __uint_as_float(ub.x), __uint_as_float(ub.y), __uint_as_float(ub.z)};

__global__ __launch_bounds__(256) void k_agg(const unsigned int* __restrict__ offsets,
                                             const uint4* __restrict__ edata,
                                             const unsigned short* __restrict__ hb,
                                             unsigned short* __restrict__ gb) {
    const int n = blockIdx.x * 4 + (threadIdx.x >> 6);  // one wave per node
    if (n >= NN) return;
    const int l = threadIdx.x & 63;
    const unsigned int e0 = __builtin_amdgcn_readfirstlane(offsets[n]);
    const unsigned int e1 = __builtin_amdgcn_readfirstlane(offsets[n + 1]);
    float acc[6] = {0.f, 0.f, 0.f, 0.f, 0.f, 0.f};
    float den[6] = {0.f, 0.f, 0.f, 0.f, 0.f, 0.f};

    unsigned int e = e0;
    for (; e + 8 <= e1; e += 8) {
        const unsigned int eu = __builtin_amdgcn_readfirstlane(e);  // uniform -> s_load records
        uint4 ra[8], rb[8];
        #pragma unroll
        for (int j = 0; j < 8; j++) {
            ra[j] = edata[2 * (size_t)(eu + j)];
            rb[j] = edata[2 * (size_t)(eu + j) + 1];
        }
        float hv[8];
        #pragma unroll
        for (int j = 0; j < 8; j++) hv[j] = b2f(hb[(size_t)ra[j].x * HIDD + l]);
        #pragma unroll
        for (int j = 0; j < 8; j++) {
            W6(ra[j], rb[j], wj)
            #pragma unroll
            for (int hd = 0; hd < 6; hd++) {
                acc[hd] = fmaf(wj[hd], hv[j], acc[hd]);
                den[hd] += wj[hd];
            }
        }
    }
    for (; e + 4 <= e1; e += 4) {
        const unsigned int eu = __builtin_amdgcn_readfirstlane(e);
        const uint4 a0 = edata[2 * (size_t)eu + 0], b0 = edata[2 * (size_t)eu + 1];
        const uint4 a1 = edata[2 * (size_t)eu + 2], b1 = edata[2 * (size_t)eu + 3];
        const uint4 a2 = edata[2 * (size_t)eu + 4], b2 = edata[2 * (size_t)eu + 5];
        const uint4 a3 = edata[2 * (size_t)eu + 6], b3 = edata[2 * (size_t)eu + 7];
        const float h0 = b2f(hb[(size_t)a0.x * HIDD + l]);
        const float h1 = b2f(hb[(size_t)a1.x * HIDD + l]);
        const float h2 = b2f(hb[(size_t)a2.x * HIDD + l]);
        const float h3 = b2f(hb[(size_t)a3.x * HIDD + l]);
        W6(a0, b0, w0) W6(a1, b1, w1) W6(a2, b2, w2) W6(a3, b3, w3)
        #pragma unroll
        for (int hd = 0; hd < 6; hd++) {
            acc[hd] = fmaf(w0[hd], h0, acc[hd]);
            acc[hd] = fmaf(w1[hd], h1, acc[hd]);
            acc[hd] = fmaf(w2[hd], h2, acc[hd]);
            acc[hd] = fmaf(w3[hd], h3, acc[hd]);
            den[hd] += (w0[hd] + w1[hd]) + (w2[hd] + w3[hd]);
        }
    }
    for (; e < e1; e++) {
        const unsigned int eu = __builtin_amdgcn_readfirstlane(e);
        const uint4 ua = edata[2 * (size_t)eu], ub = edata[2 * (size_t)eu + 1];
        const float hv = b2f(hb[(size_t)ua.x * HIDD + l]);
        W6(ua, ub, wv)
        #pragma unroll
        for (int hd = 0; hd < 6; hd++) {
            acc[hd] = fmaf(wv[hd], hv, acc[hd]);
            den[hd] += wv[hd];
        }
    }
    #pragma unroll
    for (int hd = 0; hd < 6; hd++)
        gb[(size_t)n * FD + hd * 64 + l] = f2b(acc[hd] / den[hd]);
}

// ---- k_tail: out = [hb | lrelu(gb@blockdiag(Wg)+bg)] @ W_lin + b_lin  (3 barriers/head) ----
__global__ __launch_bounds__(256) void k_tail(const unsigned short* __restrict__ gb,
                                              const unsigned short* __restrict__ hb,
                                              const unsigned short* __restrict__ Wgt,
                                              const float* __restrict__ bg,
                                              const unsigned short* __restrict__ Wlt,  // [64][448]
                                              const float* __restrict__ bl,
                                              float* __restrict__ out) {
    __shared__ unsigned short As[64][72];   // A operand (hb, then gb head tiles)
    __shared__ unsigned short BsG[64][72];  // gat2 B (Wgt[hd])
    __shared__ unsigned short BsL[64][72];  // fin  B (Wlt block)
    __shared__ unsigned short Ct[64][72];   // gat2 output staging
    const int t  = threadIdx.x;
    const int n0 = blockIdx.x * 64;
    const int w = t >> 6, l = t & 63;
    const int fr = l & 15, fq = l >> 4;
    const int ar = t >> 2, ac = (t & 3) * 16;
    int arg = n0 + ar; if (arg >= NN) arg = NN - 1;

    f32x4 oacc[4];
    #pragma unroll
    for (int nb = 0; nb < 4; nb++) oacc[nb] = (f32x4){0.f, 0.f, 0.f, 0.f};

    {   // kt = 0: A = hb tile, B = Wlt[:, 0:64]
        const uint4* hp = (const uint4*)(hb + (size_t)arg * HIDD + ac);
        uint4 aA = hp[0], aB = hp[1];
        const uint4* wp = (const uint4*)(Wlt + (size_t)ar * CATK + 0 + ac);
        uint4 b0 = wp[0], b1 = wp[1];
        *(uint4*)&As[ar][ac]      = aA;
        *(uint4*)&As[ar][ac + 8]  = aB;
        *(uint4*)&BsL[ar][ac]     = b0;
        *(uint4*)&BsL[ar][ac + 8] = b1;
        __syncthreads();
        #pragma unroll
        for (int ks = 0; ks < 2; ks++) {
            short8 af = *(const short8*)&As[w * 16 + fr][ks * 32 + fq * 8];
            #pragma unroll
            for (int nb = 0; nb < 4; nb++) {
                short8 bf = *(const short8*)&BsL[nb * 16 + fr][ks * 32 + fq * 8];
                oacc[nb] = __builtin_amdgcn_mfma_f32_16x16x32_bf16(af, bf, oacc[nb], 0, 0, 0);
            }
        }
    }

    for (int hd = 0; hd < 6; hd++) {
        __syncthreads();   // previous iter's MFMA reads (As/BsG/BsL/Ct) complete
        {   // stage A = gb tile (head hd), BsG = Wgt[hd], BsL = Wlt[:, 64+hd*64 ..]
            const uint4* gp = (const uint4*)(gb + (size_t)arg * FD + hd * 64 + ac);
            uint4 aA = gp[0], aB = gp[1];
            const uint4* wpg = (const uint4*)(Wgt + (size_t)hd * 4096 + ar * 64 + ac);
            uint4 g0 = wpg[0], g1 = wpg[1];
            const uint4* wpl = (const uint4*)(Wlt + (size_t)ar * CATK + 64 + hd * 64 + ac);
            uint4 l0 = wpl[0], l1 = wpl[1];
            *(uint4*)&As[ar][ac]      = aA;
            *(uint4*)&As[ar][ac + 8]  = aB;
            *(uint4*)&BsG[ar][ac]     = g0;
            *(uint4*)&BsG[ar][ac + 8] = g1;
            *(uint4*)&BsL[ar][ac]     = l0;
            *(uint4*)&BsL[ar][ac + 8] = l1;
        }
        __syncthreads();
        f32x4 acc2[4];
        #pragma unroll
        for (int nb = 0; nb < 4; nb++) acc2[nb] = (f32x4){0.f, 0.f, 0.f, 0.f};
        #pragma unroll
        for (int ks = 0; ks < 2; ks++) {
            short8 af = *(const short8*)&As[w * 16 + fr][ks * 32 + fq * 8];
            #pragma unroll
            for (int nb = 0; nb < 4; nb++) {
                short8 bf = *(const short8*)&BsG[nb * 16 + fr][ks * 32 + fq * 8];
                acc2[nb] = __builtin_amdgcn_mfma_f32_16x16x32_bf16(af, bf, acc2[nb], 0, 0, 0);
            }
        }
        #pragma unroll
        for (int nb = 0; nb < 4; nb++) {
            const int col = nb * 16 + fr;
            const float bias = bg[hd * 64 + col];
            #pragma unroll
            for (int r = 0; r < 4; r++)
                Ct[w * 16 + fq * 4 + r][col] = f2b(lrelu(acc2[nb][r] + bias, 0.01f));
        }
        __syncthreads();   // all Ct writes visible
        #pragma unroll
        for (int ks = 0; ks < 2; ks++) {
            short8 af = *(const short8*)&Ct[w * 16 + fr][ks * 32 + fq * 8];
            #pragma unroll
            for (int nb = 0; nb < 4; nb++) {
                short8 bf = *(const short8*)&BsL[nb * 16 + fr][ks * 32 + fq * 8];
                oacc[nb] = __builtin_amdgcn_mfma_f32_16x16x32_bf16(af, bf, oacc[nb], 0, 0, 0);
            }
        }
    }

    #pragma unroll
    for (int nb = 0; nb < 4; nb++) {
        const int col = nb * 16 + fr;
        const float bias = bl[col];
        #pragma unroll
        for (int r = 0; r < 4; r++) {
            const int row = n0 + w * 16 + fq * 4 + r;
            if (row < NN) out[(size_t)row * HIDD + col] = oacc[nb][r] + bias;
        }
    }
}

extern "C" void kernel_launch(void* const* d_in, const int* in_sizes, int n_in,
                              void* d_out, int out_size, void* d_ws, size_t ws_size,
                              hipStream_t stream) {
    const float* x   = (const float*)d_in[0];
    const int*   ei  = (const int*)d_in[1];
    // d_in[2] edge_weight: unused by the reference forward
    const float* Wp  = (const float*)d_in[3];
    const float* bp  = (const float*)d_in[4];
    const float* Wg  = (const float*)d_in[5];
    const float* ats = (const float*)d_in[6];
    const float* atd = (const float*)d_in[7];
    const float* bg  = (const float*)d_in[8];
    const float* Wl  = (const float*)d_in[9];
    const float* bl  = (const float*)d_in[10];
    float* out = (float*)d_out;

    char* ws_base = (char*)d_ws;
    size_t off = 0;
    auto alloc = [&](size_t bytes) -> char* {
        char* p = ws_base + off;
        off = (off + bytes + 255) & ~(size_t)255;
        return p;
    };
    unsigned short* hb      = (unsigned short*)alloc((size_t)NN * HIDD * 2);
    unsigned short* gb      = (unsigned short*)alloc((size_t)NN * FD * 2);
    float*          asrcP   = (float*)alloc((size_t)NN * 8 * 4);
    float*          adstP   = (float*)alloc((size_t)NN * 8 * 4);
    unsigned int*   counts  = (unsigned int*)alloc((size_t)NN * 4);   // contiguous with cursor
    unsigned int*   cursor  = (unsigned int*)alloc((size_t)NN * 4);
    unsigned int*   offsets = (unsigned int*)alloc((size_t)(NN + 1) * 4);
    unsigned int*   flag    = (unsigned int*)alloc(256);
    uint4*          edata   = (uint4*)alloc((size_t)E2T * 32);
    unsigned short* Wt      = (unsigned short*)alloc((size_t)64 * CURD * 2);
    unsigned short* Wgt     = (unsigned short*)alloc((size_t)6 * 64 * 64 * 2);
    unsigned short* Wlt     = (unsigned short*)alloc((size_t)64 * CATK * 2);
    float*          wsv     = (float*)alloc((size_t)6 * 64 * 4);
    float*          wdv     = (float*)alloc((size_t)6 * 64 * 4);
    if (off > ws_size) return;

    const int nb64 = (NN + 63) / 64;    // 782

    // zero counts+cursor in one async memset (they are adjacent in the workspace)
    size_t cc_bytes = (size_t)((char*)cursor - (char*)counts) + (size_t)NN * 4;
    hipMemsetAsync(counts, 0, cc_bytes, stream);

    hipLaunchKernelGGL(k_setup,   dim3(B_TOT2), dim3(256), 0, stream,
                       ei, Wp, Wl, Wg, ats, atd, counts, flag, Wt, Wlt, Wgt, wsv, wdv);
    hipLaunchKernelGGL(k_pre,     dim3(nb64), dim3(256), 0, stream, x, Wt, bp, hb);
    hipLaunchKernelGGL(k_attscan, dim3(ATTB + 1), dim3(256), 0, stream,
                       hb, wsv, wdv, counts, asrcP, adstP, offsets);
    hipLaunchKernelGGL(k_fill,    dim3((E2T + 255) / 256), dim3(256), 0, stream,
                       ei, flag, offsets, cursor, asrcP, adstP, edata);
    hipLaunchKernelGGL(k_agg,     dim3((NN + 3) / 4), dim3(256), 0, stream, offsets, edata, hb, gb);
    hipLaunchKernelGGL(k_tail,    dim3(nb64), dim3(256), 0, stream, gb, hb, Wgt, bg, Wlt, bl, out);
}

// Round 13
// 223.670 us; speedup vs baseline: 1.3310x; 1.3310x over previous
//
#include <hip/hip_runtime.h>
#include <hip/hip_bf16.h>

// GNN forward: pre-Linear -> GATConv(6 heads, self-loops, edge softmax) -> concat -> Linear
// - Aggregation identity: sum_e coef_e*(h[s]@Wg) = (sum_e coef_e*h[s])@Wg -> gather 128B bf16 rows
// - Per-edge softmax weights computed once in k_fill -> 32B f32 records {src, w0..w5, pad}
// - k_agg: readfirstlane scalar record loads, 8-edge unroll
// - Launch chain: memset(counts|cursor) -> k_setup(detect+transposes+watt+hist)
//   -> k_pre -> k_attscan(att blocks ∥ 196 bsum blocks) -> k_off -> k_fill -> k_agg -> k_tail
// - R12 lesson: single-block scan = 119us straggler (serial HBM-latency loads, no TLP).
//   Scan must be block-parallel: bsum (196 coalesced blocks) + k_off (196 blocks w/ inline scan).
// - NOTE(R6/R7 lesson): do NOT fuse a_src/a_dst into k_pre as extra MFMA columns (80-col B tile)
//   -> post-timing graph-replay divergence, mechanism unidentified. k_att stays separate.
// N=50000, E=800000 (+N self loops), CUR=512, HID=64, OUT=64, HEADS=6

#define NN    50000
#define EE    800000
#define E2T   850000
#define CURD  512
#define HIDD  64
#define FD    384        // HEADS*OUT
#define CATK  448        // HID + FD

typedef __attribute__((ext_vector_type(8))) short short8;
typedef __attribute__((ext_vector_type(4))) float f32x4;

static __device__ __forceinline__ float b2f(unsigned short u) {
    union { unsigned int i; float f; } x; x.i = ((unsigned int)u) << 16; return x.f;
}
static __device__ __forceinline__ unsigned short f2b(float f) {
    unsigned int x = __float_as_uint(f);
    unsigned int r = (x + 0x7fffu + ((x >> 16) & 1u)) >> 16;
    return (unsigned short)r;
}
static __device__ __forceinline__ unsigned int packbf(float a, float b) {
    return (unsigned int)f2b(a) | ((unsigned int)f2b(b) << 16);
}
static __device__ __forceinline__ float lrelu(float v, float a) { return v > 0.f ? v : a * v; }

// ---------------- k_setup: detect | 3 weight transposes | watt | HIST (fused) ----------------
#define B_DET2  0             // 1 block: global flag for k_fill
#define B_TRWP2 1             // 1..128:   Wt[c][k]=Wp[k][c]
#define B_TRWL2 129           // 129..240: Wlt[c][k]=Wl[k][c]
#define B_TRWG2 241           // 241..336: Wgt[h][c][k]=Wg[k][h*64+c]
#define B_WATT2 337           // 337..338: wsv/wdv
#define B_HIST2 339           // 339..3463: histogram (3125 blocks, per-block local detect)
#define B_TOT2  3464

__global__ void k_setup(const int* __restrict__ ei,
                        const float* __restrict__ Wp, const float* __restrict__ Wl,
                        const float* __restrict__ Wg,
                        const float* __restrict__ atts, const float* __restrict__ attd,
                        unsigned int* __restrict__ counts, unsigned int* __restrict__ flag,
                        unsigned short* __restrict__ Wt, unsigned short* __restrict__ Wlt,
                        unsigned short* __restrict__ Wgt,
                        float* __restrict__ wsv, float* __restrict__ wdv) {
    __shared__ unsigned int anyv;
    const int b = blockIdx.x, t = threadIdx.x;
    if (b >= B_HIST2) {                               // histogram w/ local int64 detect
        if (t == 0) anyv = 0u;
        __syncthreads();
        unsigned int v = 0;
        for (int i = t; i < 2048; i += 256) v |= (unsigned int)ei[2 * i + 1];
        atomicOr(&anyv, v);
        __syncthreads();
        const bool wide = (anyv == 0u);
        int e = (b - B_HIST2) * 256 + t;
        if (e < EE) {
            int d = wide ? ei[2 * (EE + e)] : ei[EE + e];
            atomicAdd(&counts[d], 1u);
        }
    } else if (b == B_DET2) {
        if (t == 0) anyv = 0u;
        __syncthreads();
        unsigned int v = 0;
        for (int i = t; i < 2048; i += 256) v |= (unsigned int)ei[2 * i + 1];
        atomicOr(&anyv, v);
        __syncthreads();
        if (t == 0) *flag = (anyv == 0u) ? 1u : 0u;   // 1 => int64 layout
    } else if (b < B_TRWL2) {
        int i = (b - B_TRWP2) * 256 + t;              // Wt[c][k]=Wp[k][c], K=512
        int c = i >> 9, k = i & 511;
        Wt[i] = f2b(Wp[k * 64 + c]);
    } else if (b < B_TRWG2) {
        int i = (b - B_TRWL2) * 256 + t;
        if (i < 64 * CATK) {
            int c = i / CATK, k = i - c * CATK;
            Wlt[i] = f2b(Wl[k * 64 + c]);
        }
    } else if (b < B_WATT2) {
        int i = (b - B_TRWG2) * 256 + t;
        int hd = i >> 12, rem = i & 4095, c = rem >> 6, k = rem & 63;
        Wgt[i] = f2b(Wg[k * FD + hd * 64 + c]);
    } else {
        int j = (b - B_WATT2) * 256 + t;              // 384 total
        if (j < 384) {
            int hd = j >> 6, k = j & 63;
            float s = 0.f, d = 0.f;
            for (int c = 0; c < 64; c++) {
                float w = Wg[k * FD + hd * 64 + c];
                s = fmaf(w, atts[hd * 64 + c], s);
                d = fmaf(w, attd[hd * 64 + c], d);
            }
            wsv[j] = s; wdv[j] = d;
        }
    }
}

// ---------------- K1: hb = bf16(x @ W_pre + b_pre)  (bf16 MFMA, register-direct A) ----------------
__global__ __launch_bounds__(256) void k_pre(const float* __restrict__ x,
                                             const unsigned short* __restrict__ Wt,
                                             const float* __restrict__ bp,
                                             unsigned short* __restrict__ hb) {
    __shared__ unsigned short Bs[64][72];
    const int t  = threadIdx.x;
    const int n0 = blockIdx.x * 64;
    const int w = t >> 6, l = t & 63;
    const int fr = l & 15, fq = l >> 4;
    const int ar = t >> 2, ac = (t & 3) * 16;
    int arow = n0 + w * 16 + fr; if (arow >= NN) arow = NN - 1;
    f32x4 acc[4];
    #pragma unroll
    for (int nb = 0; nb < 4; nb++) acc[nb] = (f32x4){0.f, 0.f, 0.f, 0.f};

    for (int kt = 0; kt < CURD; kt += 64) {
        const float4* xp0 = (const float4*)(x + (size_t)arow * CURD + kt + 0 * 32 + fq * 8);
        const float4* xp1 = (const float4*)(x + (size_t)arow * CURD + kt + 1 * 32 + fq * 8);
        float4 a00 = xp0[0], a01 = xp0[1];
        float4 a10 = xp1[0], a11 = xp1[1];
        const uint4* wp = (const uint4*)(Wt + (size_t)ar * CURD + kt + ac);
        uint4 b0 = wp[0], b1 = wp[1];
        __syncthreads();
        *(uint4*)&Bs[ar][ac]     = b0;
        *(uint4*)&Bs[ar][ac + 8] = b1;
        __syncthreads();
        unsigned int afw[2][4] = {
            {packbf(a00.x,a00.y), packbf(a00.z,a00.w), packbf(a01.x,a01.y), packbf(a01.z,a01.w)},
            {packbf(a10.x,a10.y), packbf(a10.z,a10.w), packbf(a11.x,a11.y), packbf(a11.z,a11.w)}};
        #pragma unroll
        for (int ks = 0; ks < 2; ks++) {
            short8 af;
            __builtin_memcpy(&af, &afw[ks][0], 16);
            #pragma unroll
            for (int nb = 0; nb < 4; nb++) {
                short8 bf = *(const short8*)&Bs[nb * 16 + fr][ks * 32 + fq * 8];
                acc[nb] = __builtin_amdgcn_mfma_f32_16x16x32_bf16(af, bf, acc[nb], 0, 0, 0);
            }
        }
    }
    #pragma unroll
    for (int nb = 0; nb < 4; nb++) {
        const int col = nb * 16 + fr;
        const float bias = bp[col];
        #pragma unroll
        for (int r = 0; r < 4; r++) {
            const int row = n0 + w * 16 + fq * 4 + r;
            if (row < NN) hb[(size_t)row * HIDD + col] = f2b(acc[nb][r] + bias);
        }
    }
}

// ---- k_attscan: blocks 0..12499 att; blocks 12500..12695 per-block sums of (counts+1) ----
#define ATTB 12500
#define NBS  196              // scan blocks; 196*256 = 50176 >= NN

__global__ __launch_bounds__(256) void k_attscan(const unsigned short* __restrict__ hb,
                                                 const float* __restrict__ ws,
                                                 const float* __restrict__ wd,
                                                 const unsigned int* __restrict__ counts,
                                                 float* __restrict__ asrcP, float* __restrict__ adstP,
                                                 unsigned int* __restrict__ bsum) {
    const int b = blockIdx.x, t = threadIdx.x;
    if (b < ATTB) {
        const int n = b * 4 + (t >> 6);
        if (n >= NN) return;
        const int l = t & 63;
        const float v = b2f(hb[(size_t)n * HIDD + l]);
        float ps[6], pd[6];
        #pragma unroll
        for (int hd = 0; hd < 6; hd++) {
            ps[hd] = v * ws[hd * 64 + l];
            pd[hd] = v * wd[hd * 64 + l];
        }
        #pragma unroll
        for (int o = 32; o > 0; o >>= 1) {
            #pragma unroll
            for (int hd = 0; hd < 6; hd++) {
                ps[hd] += __shfl_xor(ps[hd], o, 64);
                pd[hd] += __shfl_xor(pd[hd], o, 64);
            }
        }
        if (l == 0) {
            #pragma unroll
            for (int hd = 0; hd < 6; hd++) {
                asrcP[(size_t)n * 8 + hd] = ps[hd];
                adstP[(size_t)n * 8 + hd] = pd[hd];
            }
        }
    } else {
        __shared__ unsigned int wt[4];
        const int bs = b - ATTB;
        const int w = t >> 6, l = t & 63;
        int i = bs * 256 + t;
        unsigned int v = (i < NN) ? counts[i] + 1u : 0u;   // +1 = self loop
        #pragma unroll
        for (int o = 32; o > 0; o >>= 1) v += __shfl_xor(v, o, 64);
        if (l == 0) wt[w] = v;
        __syncthreads();
        if (t == 0) bsum[bs] = wt[0] + wt[1] + wt[2] + wt[3];
    }
}

// ---------------- k_off: offsets (inline redundant scan of 196 block sums) ----------------
__global__ __launch_bounds__(256) void k_off(const unsigned int* __restrict__ counts,
                                             const unsigned int* __restrict__ bsum,
                                             unsigned int* __restrict__ offsets) {
    __shared__ unsigned int sc[256];
    __shared__ unsigned int wt[4];
    const int t = threadIdx.x, w = t >> 6, l = t & 63;
    unsigned int bv = (t < NBS) ? bsum[t] : 0u;
    sc[t] = bv;
    __syncthreads();
    for (int o = 1; o < 256; o <<= 1) {
        unsigned int xv = (t >= o) ? sc[t - o] : 0u;
        __syncthreads();
        sc[t] += xv;
        __syncthreads();
    }
    const unsigned int bpre = sc[blockIdx.x] -
        ((blockIdx.x < NBS) ? bsum[blockIdx.x] : 0u);   // exclusive prefix for this block

    int i = blockIdx.x * 256 + t;
    unsigned int v = (i < NN) ? counts[i] + 1u : 0u;    // +1 = self loop
    unsigned int incl = v;
    #pragma unroll
    for (int o = 1; o < 64; o <<= 1) {
        unsigned int xv = __shfl_up(incl, o, 64);
        if (l >= o) incl += xv;
    }
    if (l == 63) wt[w] = incl;
    __syncthreads();
    unsigned int woff = 0;
    #pragma unroll
    for (int ww = 0; ww < 4; ww++) woff += (ww < w) ? wt[ww] : 0u;
    const unsigned int base = bpre + woff;
    if (i < NN) offsets[i] = base + incl - v;
    if (i == NN - 1) offsets[NN] = base + incl;
}

// ---------------- CSR fill + per-edge weights: edata[2*pos..] = {src, 6 x f32 w, 0} ----------------
__global__ void k_fill(const int* __restrict__ ei, const unsigned int* __restrict__ flag,
                       const unsigned int* __restrict__ offsets, unsigned int* __restrict__ cursor,
                       const float* __restrict__ asrcP, const float* __restrict__ adstP,
                       uint4* __restrict__ edata) {
    int e = blockIdx.x * 256 + threadIdx.x;
    if (e >= E2T) return;
    const bool wide = (*flag != 0u);
    int s, d;
    if (e < EE) {
        s = wide ? ei[2 * e] : ei[e];
        d = wide ? ei[2 * (EE + e)] : ei[EE + e];
    } else { s = d = e - EE; }
    unsigned int pos = offsets[d] + atomicAdd(&cursor[d], 1u);
    const float4 s0 = *(const float4*)(asrcP + (size_t)s * 8);
    const float2 s1 = *(const float2*)(asrcP + (size_t)s * 8 + 4);
    const float4 d0 = *(const float4*)(adstP + (size_t)d * 8);
    const float2 d1 = *(const float2*)(adstP + (size_t)d * 8 + 4);
    const float as[6] = {s0.x, s0.y, s0.z, s0.w, s1.x, s1.y};
    const float ad[6] = {d0.x, d0.y, d0.z, d0.w, d1.x, d1.y};
    float wv[6];
    #pragma unroll
    for (int hd = 0; hd < 6; hd++) {
        float a = as[hd] + ad[hd];
        a = fmaxf(a, 0.2f * a);                 // leaky_relu 0.2
        wv[hd] = __expf(a);                     // shift skipped: alpha O(1), softmax shift-invariant
    }
    uint4 u0, u1;
    u0.x = (unsigned int)s;
    u0.y = __float_as_uint(wv[0]); u0.z = __float_as_uint(wv[1]); u0.w = __float_as_uint(wv[2]);
    u1.x = __float_as_uint(wv[3]); u1.y = __float_as_uint(wv[4]); u1.z = __float_as_uint(wv[5]);
    u1.w = 0u;
    edata[2 * (size_t)pos]     = u0;
    edata[2 * (size_t)pos + 1] = u1;
}

// ---------------- k_agg: scalar record loads (8-edge unroll) + coalesced row gather ----------------
#define W6(ua, ub, nm) \
    const float nm[6] = {__uint_as_float(ua.y), __uint_as_float(ua.z), __uint_as_float(ua.w), \
                         __uint_as_float(ub.x), __uint_as_float(ub.y), __uint_as_float(ub.z)};

__global__ __launch_bounds__(256) void k_agg(const unsigned int* __restrict__ offsets,
                                             const uint4* __restrict__ edata,
                                             const unsigned short* __restrict__ hb,
                                             unsigned short* __restrict__ gb) {
    const int n = blockIdx.x * 4 + (threadIdx.x >> 6);  // one wave per node
    if (n >= NN) return;
    const int l = threadIdx.x & 63;
    const unsigned int e0 = __builtin_amdgcn_readfirstlane(offsets[n]);
    const unsigned int e1 = __builtin_amdgcn_readfirstlane(offsets[n + 1]);
    float acc[6] = {0.f, 0.f, 0.f, 0.f, 0.f, 0.f};
    float den[6] = {0.f, 0.f, 0.f, 0.f, 0.f, 0.f};

    unsigned int e = e0;
    for (; e + 8 <= e1; e += 8) {
        const unsigned int eu = __builtin_amdgcn_readfirstlane(e);  // uniform -> s_load records
        uint4 ra[8], rb[8];
        #pragma unroll
        for (int j = 0; j < 8; j++) {
            ra[j] = edata[2 * (size_t)(eu + j)];
            rb[j] = edata[2 * (size_t)(eu + j) + 1];
        }
        float hv[8];
        #pragma unroll
        for (int j = 0; j < 8; j++) hv[j] = b2f(hb[(size_t)ra[j].x * HIDD + l]);
        #pragma unroll
        for (int j = 0; j < 8; j++) {
            W6(ra[j], rb[j], wj)
            #pragma unroll
            for (int hd = 0; hd < 6; hd++) {
                acc[hd] = fmaf(wj[hd], hv[j], acc[hd]);
                den[hd] += wj[hd];
            }
        }
    }
    for (; e + 4 <= e1; e += 4) {
        const unsigned int eu = __builtin_amdgcn_readfirstlane(e);
        const uint4 a0 = edata[2 * (size_t)eu + 0], b0 = edata[2 * (size_t)eu + 1];
        const uint4 a1 = edata[2 * (size_t)eu + 2], b1 = edata[2 * (size_t)eu + 3];
        const uint4 a2 = edata[2 * (size_t)eu + 4], b2 = edata[2 * (size_t)eu + 5];
        const uint4 a3 = edata[2 * (size_t)eu + 6], b3 = edata[2 * (size_t)eu + 7];
        const float h0 = b2f(hb[(size_t)a0.x * HIDD + l]);
        const float h1 = b2f(hb[(size_t)a1.x * HIDD + l]);
        const float h2 = b2f(hb[(size_t)a2.x * HIDD + l]);
        const float h3 = b2f(hb[(size_t)a3.x * HIDD + l]);
        W6(a0, b0, w0) W6(a1, b1, w1) W6(a2, b2, w2) W6(a3, b3, w3)
        #pragma unroll
        for (int hd = 0; hd < 6; hd++) {
            acc[hd] = fmaf(w0[hd], h0, acc[hd]);
            acc[hd] = fmaf(w1[hd], h1, acc[hd]);
            acc[hd] = fmaf(w2[hd], h2, acc[hd]);
            acc[hd] = fmaf(w3[hd], h3, acc[hd]);
            den[hd] += (w0[hd] + w1[hd]) + (w2[hd] + w3[hd]);
        }
    }
    for (; e < e1; e++) {
        const unsigned int eu = __builtin_amdgcn_readfirstlane(e);
        const uint4 ua = edata[2 * (size_t)eu], ub = edata[2 * (size_t)eu + 1];
        const float hv = b2f(hb[(size_t)ua.x * HIDD + l]);
        W6(ua, ub, wv)
        #pragma unroll
        for (int hd = 0; hd < 6; hd++) {
            acc[hd] = fmaf(wv[hd], hv, acc[hd]);
            den[hd] += wv[hd];
        }
    }
    #pragma unroll
    for (int hd = 0; hd < 6; hd++)
        gb[(size_t)n * FD + hd * 64 + l] = f2b(acc[hd] / den[hd]);
}

// ---- k_tail: out = [hb | lrelu(gb@blockdiag(Wg)+bg)] @ W_lin + b_lin  (3 barriers/head) ----
__global__ __launch_bounds__(256) void k_tail(const unsigned short* __restrict__ gb,
                                              const unsigned short* __restrict__ hb,
                                              const unsigned short* __restrict__ Wgt,
                                              const float* __restrict__ bg,
                                              const unsigned short* __restrict__ Wlt,  // [64][448]
                                              const float* __restrict__ bl,
                                              float* __restrict__ out) {
    __shared__ unsigned short As[64][72];   // A operand (hb, then gb head tiles)
    __shared__ unsigned short BsG[64][72];  // gat2 B (Wgt[hd])
    __shared__ unsigned short BsL[64][72];  // fin  B (Wlt block)
    __shared__ unsigned short Ct[64][72];   // gat2 output staging
    const int t  = threadIdx.x;
    const int n0 = blockIdx.x * 64;
    const int w = t >> 6, l = t & 63;
    const int fr = l & 15, fq = l >> 4;
    const int ar = t >> 2, ac = (t & 3) * 16;
    int arg = n0 + ar; if (arg >= NN) arg = NN - 1;

    f32x4 oacc[4];
    #pragma unroll
    for (int nb = 0; nb < 4; nb++) oacc[nb] = (f32x4){0.f, 0.f, 0.f, 0.f};

    {   // kt = 0: A = hb tile, B = Wlt[:, 0:64]
        const uint4* hp = (const uint4*)(hb + (size_t)arg * HIDD + ac);
        uint4 aA = hp[0], aB = hp[1];
        const uint4* wp = (const uint4*)(Wlt + (size_t)ar * CATK + 0 + ac);
        uint4 b0 = wp[0], b1 = wp[1];
        *(uint4*)&As[ar][ac]      = aA;
        *(uint4*)&As[ar][ac + 8]  = aB;
        *(uint4*)&BsL[ar][ac]     = b0;
        *(uint4*)&BsL[ar][ac + 8] = b1;
        __syncthreads();
        #pragma unroll
        for (int ks = 0; ks < 2; ks++) {
            short8 af = *(const short8*)&As[w * 16 + fr][ks * 32 + fq * 8];
            #pragma unroll
            for (int nb = 0; nb < 4; nb++) {
                short8 bf = *(const short8*)&BsL[nb * 16 + fr][ks * 32 + fq * 8];
                oacc[nb] = __builtin_amdgcn_mfma_f32_16x16x32_bf16(af, bf, oacc[nb], 0, 0, 0);
            }
        }
    }

    for (int hd = 0; hd < 6; hd++) {
        __syncthreads();   // previous iter's MFMA reads (As/BsG/BsL/Ct) complete
        {   // stage A = gb tile (head hd), BsG = Wgt[hd], BsL = Wlt[:, 64+hd*64 ..]
            const uint4* gp = (const uint4*)(gb + (size_t)arg * FD + hd * 64 + ac);
            uint4 aA = gp[0], aB = gp[1];
            const uint4* wpg = (const uint4*)(Wgt + (size_t)hd * 4096 + ar * 64 + ac);
            uint4 g0 = wpg[0], g1 = wpg[1];
            const uint4* wpl = (const uint4*)(Wlt + (size_t)ar * CATK + 64 + hd * 64 + ac);
            uint4 l0 = wpl[0], l1 = wpl[1];
            *(uint4*)&As[ar][ac]      = aA;
            *(uint4*)&As[ar][ac + 8]  = aB;
            *(uint4*)&BsG[ar][ac]     = g0;
            *(uint4*)&BsG[ar][ac + 8] = g1;
            *(uint4*)&BsL[ar][ac]     = l0;
            *(uint4*)&BsL[ar][ac + 8] = l1;
        }
        __syncthreads();
        f32x4 acc2[4];
        #pragma unroll
        for (int nb = 0; nb < 4; nb++) acc2[nb] = (f32x4){0.f, 0.f, 0.f, 0.f};
        #pragma unroll
        for (int ks = 0; ks < 2; ks++) {
            short8 af = *(const short8*)&As[w * 16 + fr][ks * 32 + fq * 8];
            #pragma unroll
            for (int nb = 0; nb < 4; nb++) {
                short8 bf = *(const short8*)&BsG[nb * 16 + fr][ks * 32 + fq * 8];
                acc2[nb] = __builtin_amdgcn_mfma_f32_16x16x32_bf16(af, bf, acc2[nb], 0, 0, 0);
            }
        }
        #pragma unroll
        for (int nb = 0; nb < 4; nb++) {
            const int col = nb * 16 + fr;
            const float bias = bg[hd * 64 + col];
            #pragma unroll
            for (int r = 0; r < 4; r++)
                Ct[w * 16 + fq * 4 + r][col] = f2b(lrelu(acc2[nb][r] + bias, 0.01f));
        }
        __syncthreads();   // all Ct writes visible
        #pragma unroll
        for (int ks = 0; ks < 2; ks++) {
            short8 af = *(const short8*)&Ct[w * 16 + fr][ks * 32 + fq * 8];
            #pragma unroll
            for (int nb = 0; nb < 4; nb++) {
                short8 bf = *(const short8*)&BsL[nb * 16 + fr][ks * 32 + fq * 8];
                oacc[nb] = __builtin_amdgcn_mfma_f32_16x16x32_bf16(af, bf, oacc[nb], 0, 0, 0);
            }
        }
    }

    #pragma unroll
    for (int nb = 0; nb < 4; nb++) {
        const int col = nb * 16 + fr;
        const float bias = bl[col];
        #pragma unroll
        for (int r = 0; r < 4; r++) {
            const int row = n0 + w * 16 + fq * 4 + r;
            if (row < NN) out[(size_t)row * HIDD + col] = oacc[nb][r] + bias;
        }
    }
}

extern "C" void kernel_launch(void* const* d_in, const int* in_sizes, int n_in,
                              void* d_out, int out_size, void* d_ws, size_t ws_size,
                              hipStream_t stream) {
    const float* x   = (const float*)d_in[0];
    const int*   ei  = (const int*)d_in[1];
    // d_in[2] edge_weight: unused by the reference forward
    const float* Wp  = (const float*)d_in[3];
    const float* bp  = (const float*)d_in[4];
    const float* Wg  = (const float*)d_in[5];
    const float* ats = (const float*)d_in[6];
    const float* atd = (const float*)d_in[7];
    const float* bg  = (const float*)d_in[8];
    const float* Wl  = (const float*)d_in[9];
    const float* bl  = (const float*)d_in[10];
    float* out = (float*)d_out;

    char* ws_base = (char*)d_ws;
    size_t off = 0;
    auto alloc = [&](size_t bytes) -> char* {
        char* p = ws_base + off;
        off = (off + bytes + 255) & ~(size_t)255;
        return p;
    };
    unsigned short* hb      = (unsigned short*)alloc((size_t)NN * HIDD * 2);
    unsigned short* gb      = (unsigned short*)alloc((size_t)NN * FD * 2);
    float*          asrcP   = (float*)alloc((size_t)NN * 8 * 4);
    float*          adstP   = (float*)alloc((size_t)NN * 8 * 4);
    unsigned int*   counts  = (unsigned int*)alloc((size_t)NN * 4);   // contiguous with cursor
    unsigned int*   cursor  = (unsigned int*)alloc((size_t)NN * 4);
    unsigned int*   offsets = (unsigned int*)alloc((size_t)(NN + 1) * 4);
    unsigned int*   flag    = (unsigned int*)alloc(256);
    unsigned int*   bsum    = (unsigned int*)alloc((size_t)256 * 4);
    uint4*          edata   = (uint4*)alloc((size_t)E2T * 32);
    unsigned short* Wt      = (unsigned short*)alloc((size_t)64 * CURD * 2);
    unsigned short* Wgt     = (unsigned short*)alloc((size_t)6 * 64 * 64 * 2);
    unsigned short* Wlt     = (unsigned short*)alloc((size_t)64 * CATK * 2);
    float*          wsv     = (float*)alloc((size_t)6 * 64 * 4);
    float*          wdv     = (float*)alloc((size_t)6 * 64 * 4);
    if (off > ws_size) return;

    const int nb64 = (NN + 63) / 64;    // 782

    // zero counts+cursor in one async memset (they are adjacent in the workspace)
    size_t cc_bytes = (size_t)((char*)cursor - (char*)counts) + (size_t)NN * 4;
    hipMemsetAsync(counts, 0, cc_bytes, stream);

    hipLaunchKernelGGL(k_setup,   dim3(B_TOT2), dim3(256), 0, stream,
                       ei, Wp, Wl, Wg, ats, atd, counts, flag, Wt, Wlt, Wgt, wsv, wdv);
    hipLaunchKernelGGL(k_pre,     dim3(nb64), dim3(256), 0, stream, x, Wt, bp, hb);
    hipLaunchKernelGGL(k_attscan, dim3(ATTB + NBS), dim3(256), 0, stream,
                       hb, wsv, wdv, counts, asrcP, adstP, bsum);
    hipLaunchKernelGGL(k_off,     dim3(NBS), dim3(256), 0, stream, counts, bsum, offsets);
    hipLaunchKernelGGL(k_fill,    dim3((E2T + 255) / 256), dim3(256), 0, stream,
                       ei, flag, offsets, cursor, asrcP, adstP, edata);
    hipLaunchKernelGGL(k_agg,     dim3((NN + 3) / 4), dim3(256), 0, stream, offsets, edata, hb, gb);
    hipLaunchKernelGGL(k_tail,    dim3(nb64), dim3(256), 0, stream, gb, hb, Wgt, bg, Wlt, bl, out);
}

// Round 14
// 209.667 us; speedup vs baseline: 1.4199x; 1.0668x over previous
//
#include <hip/hip_runtime.h>
#include <hip/hip_bf16.h>

// GNN forward: pre-Linear -> GATConv(6 heads, self-loops, edge softmax) -> concat -> Linear
// - Aggregation identity: sum_e coef_e*(h[s]@Wg) = (sum_e coef_e*h[s])@Wg -> gather 128B bf16 rows
// - Per-edge softmax weights computed once in k_fill -> 16B f16 records {src, 6 x f16 w} (R5 fmt)
// - k_agg: readfirstlane scalar record loads (s_load_dwordx4/record), 8-edge unroll
// - k_tail: separate BsG/BsL LDS buffers -> 3 barriers/head instead of 4
// - R12/R13 lesson: launch-fusion bundle (hist-in-setup, single-block scan) was net NEGATIVE;
//   this is the R10 structure (best measured 215.7us) + f16 records + tail barrier split.
// - NOTE(R6/R7 lesson): do NOT fuse a_src/a_dst into k_pre as extra MFMA columns (80-col B tile)
//   -> post-timing graph-replay divergence, mechanism unidentified. k_att stays separate.
// N=50000, E=800000 (+N self loops), CUR=512, HID=64, OUT=64, HEADS=6

#define NN    50000
#define EE    800000
#define E2T   850000
#define CURD  512
#define HIDD  64
#define FD    384        // HEADS*OUT
#define CATK  448        // HID + FD

typedef __attribute__((ext_vector_type(8))) short short8;
typedef __attribute__((ext_vector_type(4))) float f32x4;

static __device__ __forceinline__ float b2f(unsigned short u) {
    union { unsigned int i; float f; } x; x.i = ((unsigned int)u) << 16; return x.f;
}
static __device__ __forceinline__ unsigned short f2b(float f) {
    unsigned int x = __float_as_uint(f);
    unsigned int r = (x + 0x7fffu + ((x >> 16) & 1u)) >> 16;
    return (unsigned short)r;
}
static __device__ __forceinline__ unsigned int packbf(float a, float b) {
    return (unsigned int)f2b(a) | ((unsigned int)f2b(b) << 16);
}
static __device__ __forceinline__ unsigned short f2h(float f) {
    _Float16 h = (_Float16)f; unsigned short u; __builtin_memcpy(&u, &h, 2); return u;
}
static __device__ __forceinline__ float h2f(unsigned short u) {
    _Float16 h; __builtin_memcpy(&h, &u, 2); return (float)h;
}
static __device__ __forceinline__ float lrelu(float v, float a) { return v > 0.f ? v : a * v; }

// ---------------- k_setup: init + detect + 3 weight transposes + watt (R10 structure) ----------
#define B_INIT 196
#define B_DET  196
#define B_TRWP 197            // 128 blocks: Wt[c][k]=Wp[k][c]
#define B_TRWL 325            // 112 blocks: Wlt[c][k]=Wl[k][c]
#define B_TRWG 437            // 96 blocks:  Wgt[h][c][k]=Wg[k][h*64+c]
#define B_WATT 533            // 2 blocks:   wsv/wdv[h][k] = sum_c Wg[k][h*64+c]*att[h][c]
#define B_TOT  535

__global__ void k_setup(const int* __restrict__ ei,
                        const float* __restrict__ Wp, const float* __restrict__ Wl,
                        const float* __restrict__ Wg,
                        const float* __restrict__ atts, const float* __restrict__ attd,
                        unsigned int* __restrict__ counts, unsigned int* __restrict__ cursor,
                        unsigned int* __restrict__ flag,
                        unsigned short* __restrict__ Wt, unsigned short* __restrict__ Wlt,
                        unsigned short* __restrict__ Wgt,
                        float* __restrict__ wsv, float* __restrict__ wdv) {
    __shared__ unsigned int anyv;
    const int b = blockIdx.x, t = threadIdx.x;
    if (b < B_INIT) {
        int i = b * 256 + t;
        if (i < NN) { counts[i] = 1u; cursor[i] = 0u; }
    } else if (b == B_DET) {
        if (t == 0) anyv = 0u;
        __syncthreads();
        unsigned int v = 0;
        for (int i = t; i < 2048; i += 256) v |= (unsigned int)ei[2 * i + 1];
        atomicOr(&anyv, v);
        __syncthreads();
        if (t == 0) *flag = (anyv == 0u) ? 1u : 0u;   // 1 => int64 layout
    } else if (b < B_TRWL) {
        int i = (b - B_TRWP) * 256 + t;               // Wt[c][k]=Wp[k][c], K=512
        int c = i >> 9, k = i & 511;
        Wt[i] = f2b(Wp[k * 64 + c]);
    } else if (b < B_TRWG) {
        int i = (b - B_TRWL) * 256 + t;
        if (i < 64 * CATK) {
            int c = i / CATK, k = i - c * CATK;
            Wlt[i] = f2b(Wl[k * 64 + c]);
        }
    } else if (b < B_WATT) {
        int i = (b - B_TRWG) * 256 + t;
        int hd = i >> 12, rem = i & 4095, c = rem >> 6, k = rem & 63;
        Wgt[i] = f2b(Wg[k * FD + hd * 64 + c]);
    } else {
        int j = (b - B_WATT) * 256 + t;               // 384 total
        if (j < 384) {
            int hd = j >> 6, k = j & 63;
            float s = 0.f, d = 0.f;
            for (int c = 0; c < 64; c++) {
                float w = Wg[k * FD + hd * 64 + c];
                s = fmaf(w, atts[hd * 64 + c], s);
                d = fmaf(w, attd[hd * 64 + c], d);
            }
            wsv[j] = s; wdv[j] = d;
        }
    }
}

// ---------------- K1: hb = bf16(x @ W_pre + b_pre)  (bf16 MFMA, f32 accum) ----------------
__global__ __launch_bounds__(256) void k_pre(const float* __restrict__ x,
                                             const unsigned short* __restrict__ Wt,
                                             const float* __restrict__ bp,
                                             unsigned short* __restrict__ hb) {
    __shared__ unsigned short As[64][72];
    __shared__ unsigned short Bs[64][72];
    const int t  = threadIdx.x;
    const int n0 = blockIdx.x * 64;
    const int w = t >> 6, l = t & 63;
    const int fr = l & 15, fq = l >> 4;
    const int ar = t >> 2, ac = (t & 3) * 16;
    int arg = n0 + ar; if (arg >= NN) arg = NN - 1;
    f32x4 acc[4];
    #pragma unroll
    for (int nb = 0; nb < 4; nb++) acc[nb] = (f32x4){0.f, 0.f, 0.f, 0.f};

    for (int kt = 0; kt < CURD; kt += 64) {
        const float4* xp = (const float4*)(x + (size_t)arg * CURD + kt + ac);
        float4 a0 = xp[0], a1 = xp[1], a2 = xp[2], a3 = xp[3];
        const uint4* wp = (const uint4*)(Wt + (size_t)ar * CURD + kt + ac);
        uint4 b0 = wp[0], b1 = wp[1];
        __syncthreads();
        *(uint4*)&As[ar][ac]     = make_uint4(packbf(a0.x,a0.y), packbf(a0.z,a0.w),
                                              packbf(a1.x,a1.y), packbf(a1.z,a1.w));
        *(uint4*)&As[ar][ac + 8] = make_uint4(packbf(a2.x,a2.y), packbf(a2.z,a2.w),
                                              packbf(a3.x,a3.y), packbf(a3.z,a3.w));
        *(uint4*)&Bs[ar][ac]     = b0;
        *(uint4*)&Bs[ar][ac + 8] = b1;
        __syncthreads();
        #pragma unroll
        for (int ks = 0; ks < 2; ks++) {
            short8 af = *(const short8*)&As[w * 16 + fr][ks * 32 + fq * 8];
            #pragma unroll
            for (int nb = 0; nb < 4; nb++) {
                short8 bf = *(const short8*)&Bs[nb * 16 + fr][ks * 32 + fq * 8];
                acc[nb] = __builtin_amdgcn_mfma_f32_16x16x32_bf16(af, bf, acc[nb], 0, 0, 0);
            }
        }
    }
    #pragma unroll
    for (int nb = 0; nb < 4; nb++) {
        const int col = nb * 16 + fr;
        const float bias = bp[col];
        #pragma unroll
        for (int r = 0; r < 4; r++) {
            const int row = n0 + w * 16 + fq * 4 + r;
            if (row < NN) hb[(size_t)row * HIDD + col] = f2b(acc[nb][r] + bias);
        }
    }
}

// ---------------- k_att: asrcP[n][h] = hb[n,:]·ws[h]; adstP likewise (stride 8) ----------------
__global__ __launch_bounds__(256) void k_att(const unsigned short* __restrict__ hb,
                                             const float* __restrict__ ws, const float* __restrict__ wd,
                                             float* __restrict__ asrcP, float* __restrict__ adstP) {
    const int n = blockIdx.x * 4 + (threadIdx.x >> 6);
    if (n >= NN) return;
    const int l = threadIdx.x & 63;
    const float v = b2f(hb[(size_t)n * HIDD + l]);
    float ps[6], pd[6];
    #pragma unroll
    for (int hd = 0; hd < 6; hd++) {
        ps[hd] = v * ws[hd * 64 + l];
        pd[hd] = v * wd[hd * 64 + l];
    }
    #pragma unroll
    for (int o = 32; o > 0; o >>= 1) {
        #pragma unroll
        for (int hd = 0; hd < 6; hd++) {
            ps[hd] += __shfl_xor(ps[hd], o, 64);
            pd[hd] += __shfl_xor(pd[hd], o, 64);
        }
    }
    if (l == 0) {
        #pragma unroll
        for (int hd = 0; hd < 6; hd++) {
            asrcP[(size_t)n * 8 + hd] = ps[hd];
            adstP[(size_t)n * 8 + hd] = pd[hd];
        }
    }
}

// ---------------- in-degree histogram ----------------
__global__ void k_hist(const int* __restrict__ ei, const unsigned int* __restrict__ flag,
                       unsigned int* __restrict__ counts) {
    int e = blockIdx.x * 256 + threadIdx.x;
    if (e >= EE) return;
    const bool wide = (*flag != 0u);
    int d = wide ? ei[2 * (EE + e)] : ei[EE + e];
    atomicAdd(&counts[d], 1u);
}

// ---------------- scan phase 1: per-block sums ----------------
__global__ __launch_bounds__(256) void k_bsum(const unsigned int* __restrict__ counts,
                                              unsigned int* __restrict__ bsum) {
    __shared__ unsigned int wt[4];
    const int t = threadIdx.x, w = t >> 6, l = t & 63;
    int i = blockIdx.x * 256 + t;
    unsigned int v = (i < NN) ? counts[i] : 0u;
    #pragma unroll
    for (int o = 32; o > 0; o >>= 1) v += __shfl_xor(v, o, 64);
    if (l == 0) wt[w] = v;
    __syncthreads();
    if (t == 0) bsum[blockIdx.x] = wt[0] + wt[1] + wt[2] + wt[3];
}

// ---------------- scan phase 2: offsets (inline redundant scan of 196 block sums) ----------------
__global__ __launch_bounds__(256) void k_off(const unsigned int* __restrict__ counts,
                                             const unsigned int* __restrict__ bsum,
                                             unsigned int* __restrict__ offsets) {
    __shared__ unsigned int sc[256];
    __shared__ unsigned int wt[4];
    const int t = threadIdx.x, w = t >> 6, l = t & 63;
    const int nb = (NN + 255) / 256;   // 196
    unsigned int bv = (t < nb) ? bsum[t] : 0u;
    sc[t] = bv;
    __syncthreads();
    for (int o = 1; o < 256; o <<= 1) {
        unsigned int xv = (t >= o) ? sc[t - o] : 0u;
        __syncthreads();
        sc[t] += xv;
        __syncthreads();
    }
    const unsigned int bpre = sc[blockIdx.x] -
        ((blockIdx.x < nb) ? bsum[blockIdx.x] : 0u);   // exclusive prefix for this block

    int i = blockIdx.x * 256 + t;
    unsigned int v = (i < NN) ? counts[i] : 0u;
    unsigned int incl = v;
    #pragma unroll
    for (int o = 1; o < 64; o <<= 1) {
        unsigned int xv = __shfl_up(incl, o, 64);
        if (l >= o) incl += xv;
    }
    if (l == 63) wt[w] = incl;
    __syncthreads();
    unsigned int woff = 0;
    #pragma unroll
    for (int ww = 0; ww < 4; ww++) woff += (ww < w) ? wt[ww] : 0u;
    const unsigned int base = bpre + woff;
    if (i < NN) offsets[i] = base + incl - v;
    if (i == NN - 1) offsets[NN] = base + incl;
}

// ---------------- CSR fill + per-edge weights: edata[pos] = {src, 6 x f16 w} (16B) ----------------
__global__ void k_fill(const int* __restrict__ ei, const unsigned int* __restrict__ flag,
                       const unsigned int* __restrict__ offsets, unsigned int* __restrict__ cursor,
                       const float* __restrict__ asrcP, const float* __restrict__ adstP,
                       uint4* __restrict__ edata) {
    int e = blockIdx.x * 256 + threadIdx.x;
    if (e >= E2T) return;
    const bool wide = (*flag != 0u);
    int s, d;
    if (e < EE) {
        s = wide ? ei[2 * e] : ei[e];
        d = wide ? ei[2 * (EE + e)] : ei[EE + e];
    } else { s = d = e - EE; }
    unsigned int pos = offsets[d] + atomicAdd(&cursor[d], 1u);
    const float4 s0 = *(const float4*)(asrcP + (size_t)s * 8);
    const float2 s1 = *(const float2*)(asrcP + (size_t)s * 8 + 4);
    const float4 d0 = *(const float4*)(adstP + (size_t)d * 8);
    const float2 d1 = *(const float2*)(adstP + (size_t)d * 8 + 4);
    const float as[6] = {s0.x, s0.y, s0.z, s0.w, s1.x, s1.y};
    const float ad[6] = {d0.x, d0.y, d0.z, d0.w, d1.x, d1.y};
    unsigned short wh[6];
    #pragma unroll
    for (int hd = 0; hd < 6; hd++) {
        float a = as[hd] + ad[hd];
        a = fmaxf(a, 0.2f * a);                 // leaky_relu 0.2
        wh[hd] = f2h(__expf(a));                // shift skipped: alpha O(1), softmax shift-invariant
    }
    uint4 u;
    u.x = (unsigned int)s;
    u.y = (unsigned int)wh[0] | ((unsigned int)wh[1] << 16);
    u.z = (unsigned int)wh[2] | ((unsigned int)wh[3] << 16);
    u.w = (unsigned int)wh[4] | ((unsigned int)wh[5] << 16);
    edata[pos] = u;
}

// ---------------- k_agg: scalar f16-record loads (8-edge unroll) + coalesced row gather ----------
#define W6H(u, nm) \
    const float nm[6] = {h2f(u.y & 0xffff), h2f(u.y >> 16), h2f(u.z & 0xffff), \
                         h2f(u.z >> 16),    h2f(u.w & 0xffff), h2f(u.w >> 16)};

__global__ __launch_bounds__(256) void k_agg(const unsigned int* __restrict__ offsets,
                                             const uint4* __restrict__ edata,
                                             const unsigned short* __restrict__ hb,
                                             unsigned short* __restrict__ gb) {
    const int n = blockIdx.x * 4 + (threadIdx.x >> 6);  // one wave per node
    if (n >= NN) return;
    const int l = threadIdx.x & 63;
    const unsigned int e0 = __builtin_amdgcn_readfirstlane(offsets[n]);
    const unsigned int e1 = __builtin_amdgcn_readfirstlane(offsets[n + 1]);
    float acc[6] = {0.f, 0.f, 0.f, 0.f, 0.f, 0.f};
    float den[6] = {0.f, 0.f, 0.f, 0.f, 0.f, 0.f};

    unsigned int e = e0;
    for (; e + 8 <= e1; e += 8) {
        const unsigned int eu = __builtin_amdgcn_readfirstlane(e);  // uniform -> s_load records
        uint4 r[8];
        #pragma unroll
        for (int j = 0; j < 8; j++) r[j] = edata[(size_t)eu + j];
        float hv[8];
        #pragma unroll
        for (int j = 0; j < 8; j++) hv[j] = b2f(hb[(size_t)r[j].x * HIDD + l]);
        #pragma unroll
        for (int j = 0; j < 8; j++) {
            W6H(r[j], wj)
            #pragma unroll
            for (int hd = 0; hd < 6; hd++) {
                acc[hd] = fmaf(wj[hd], hv[j], acc[hd]);
                den[hd] += wj[hd];
            }
        }
    }
    for (; e + 4 <= e1; e += 4) {
        const unsigned int eu = __builtin_amdgcn_readfirstlane(e);
        uint4 r[4];
        #pragma unroll
        for (int j = 0; j < 4; j++) r[j] = edata[(size_t)eu + j];
        float hv[4];
        #pragma unroll
        for (int j = 0; j < 4; j++) hv[j] = b2f(hb[(size_t)r[j].x * HIDD + l]);
        #pragma unroll
        for (int j = 0; j < 4; j++) {
            W6H(r[j], wj)
            #pragma unroll
            for (int hd = 0; hd < 6; hd++) {
                acc[hd] = fmaf(wj[hd], hv[j], acc[hd]);
                den[hd] += wj[hd];
            }
        }
    }
    for (; e < e1; e++) {
        const unsigned int eu = __builtin_amdgcn_readfirstlane(e);
        const uint4 u = edata[(size_t)eu];
        const float hv = b2f(hb[(size_t)u.x * HIDD + l]);
        W6H(u, wv)
        #pragma unroll
        for (int hd = 0; hd < 6; hd++) {
            acc[hd] = fmaf(wv[hd], hv, acc[hd]);
            den[hd] += wv[hd];
        }
    }
    #pragma unroll
    for (int hd = 0; hd < 6; hd++)
        gb[(size_t)n * FD + hd * 64 + l] = f2b(acc[hd] / den[hd]);
}

// ---- k_tail: out = [hb | lrelu(gb@blockdiag(Wg)+bg)] @ W_lin + b_lin  (3 barriers/head) ----
__global__ __launch_bounds__(256) void k_tail(const unsigned short* __restrict__ gb,
                                              const unsigned short* __restrict__ hb,
                                              const unsigned short* __restrict__ Wgt,
                                              const float* __restrict__ bg,
                                              const unsigned short* __restrict__ Wlt,  // [64][448]
                                              const float* __restrict__ bl,
                                              float* __restrict__ out) {
    __shared__ unsigned short As[64][72];   // A operand (hb, then gb head tiles)
    __shared__ unsigned short BsG[64][72];  // gat2 B (Wgt[hd])
    __shared__ unsigned short BsL[64][72];  // fin  B (Wlt block)
    __shared__ unsigned short Ct[64][72];   // gat2 output staging
    const int t  = threadIdx.x;
    const int n0 = blockIdx.x * 64;
    const int w = t >> 6, l = t & 63;
    const int fr = l & 15, fq = l >> 4;
    const int ar = t >> 2, ac = (t & 3) * 16;
    int arg = n0 + ar; if (arg >= NN) arg = NN - 1;

    f32x4 oacc[4];
    #pragma unroll
    for (int nb = 0; nb < 4; nb++) oacc[nb] = (f32x4){0.f, 0.f, 0.f, 0.f};

    {   // kt = 0: A = hb tile, B = Wlt[:, 0:64]
        const uint4* hp = (const uint4*)(hb + (size_t)arg * HIDD + ac);
        uint4 aA = hp[0], aB = hp[1];
        const uint4* wp = (const uint4*)(Wlt + (size_t)ar * CATK + 0 + ac);
        uint4 b0 = wp[0], b1 = wp[1];
        *(uint4*)&As[ar][ac]      = aA;
        *(uint4*)&As[ar][ac + 8]  = aB;
        *(uint4*)&BsL[ar][ac]     = b0;
        *(uint4*)&BsL[ar][ac + 8] = b1;
        __syncthreads();
        #pragma unroll
        for (int ks = 0; ks < 2; ks++) {
            short8 af = *(const short8*)&As[w * 16 + fr][ks * 32 + fq * 8];
            #pragma unroll
            for (int nb = 0; nb < 4; nb++) {
                short8 bf = *(const short8*)&BsL[nb * 16 + fr][ks * 32 + fq * 8];
                oacc[nb] = __builtin_amdgcn_mfma_f32_16x16x32_bf16(af, bf, oacc[nb], 0, 0, 0);
            }
        }
    }

    for (int hd = 0; hd < 6; hd++) {
        __syncthreads();   // previous iter's MFMA reads (As/BsG/BsL/Ct) complete
        {   // stage A = gb tile (head hd), BsG = Wgt[hd], BsL = Wlt[:, 64+hd*64 ..]
            const uint4* gp = (const uint4*)(gb + (size_t)arg * FD + hd * 64 + ac);
            uint4 aA = gp[0], aB = gp[1];
            const uint4* wpg = (const uint4*)(Wgt + (size_t)hd * 4096 + ar * 64 + ac);
            uint4 g0 = wpg[0], g1 = wpg[1];
            const uint4* wpl = (const uint4*)(Wlt + (size_t)ar * CATK + 64 + hd * 64 + ac);
            uint4 l0 = wpl[0], l1 = wpl[1];
            *(uint4*)&As[ar][ac]      = aA;
            *(uint4*)&As[ar][ac + 8]  = aB;
            *(uint4*)&BsG[ar][ac]     = g0;
            *(uint4*)&BsG[ar][ac + 8] = g1;
            *(uint4*)&BsL[ar][ac]     = l0;
            *(uint4*)&BsL[ar][ac + 8] = l1;
        }
        __syncthreads();
        f32x4 acc2[4];
        #pragma unroll
        for (int nb = 0; nb < 4; nb++) acc2[nb] = (f32x4){0.f, 0.f, 0.f, 0.f};
        #pragma unroll
        for (int ks = 0; ks < 2; ks++) {
            short8 af = *(const short8*)&As[w * 16 + fr][ks * 32 + fq * 8];
            #pragma unroll
            for (int nb = 0; nb < 4; nb++) {
                short8 bf = *(const short8*)&BsG[nb * 16 + fr][ks * 32 + fq * 8];
                acc2[nb] = __builtin_amdgcn_mfma_f32_16x16x32_bf16(af, bf, acc2[nb], 0, 0, 0);
            }
        }
        #pragma unroll
        for (int nb = 0; nb < 4; nb++) {
            const int col = nb * 16 + fr;
            const float bias = bg[hd * 64 + col];
            #pragma unroll
            for (int r = 0; r < 4; r++)
                Ct[w * 16 + fq * 4 + r][col] = f2b(lrelu(acc2[nb][r] + bias, 0.01f));
        }
        __syncthreads();   // all Ct writes visible
        #pragma unroll
        for (int ks = 0; ks < 2; ks++) {
            short8 af = *(const short8*)&Ct[w * 16 + fr][ks * 32 + fq * 8];
            #pragma unroll
            for (int nb = 0; nb < 4; nb++) {
                short8 bf = *(const short8*)&BsL[nb * 16 + fr][ks * 32 + fq * 8];
                oacc[nb] = __builtin_amdgcn_mfma_f32_16x16x32_bf16(af, bf, oacc[nb], 0, 0, 0);
            }
        }
    }

    #pragma unroll
    for (int nb = 0; nb < 4; nb++) {
        const int col = nb * 16 + fr;
        const float bias = bl[col];
        #pragma unroll
        for (int r = 0; r < 4; r++) {
            const int row = n0 + w * 16 + fq * 4 + r;
            if (row < NN) out[(size_t)row * HIDD + col] = oacc[nb][r] + bias;
        }
    }
}

extern "C" void kernel_launch(void* const* d_in, const int* in_sizes, int n_in,
                              void* d_out, int out_size, void* d_ws, size_t ws_size,
                              hipStream_t stream) {
    const float* x   = (const float*)d_in[0];
    const int*   ei  = (const int*)d_in[1];
    // d_in[2] edge_weight: unused by the reference forward
    const float* Wp  = (const float*)d_in[3];
    const float* bp  = (const float*)d_in[4];
    const float* Wg  = (const float*)d_in[5];
    const float* ats = (const float*)d_in[6];
    const float* atd = (const float*)d_in[7];
    const float* bg  = (const float*)d_in[8];
    const float* Wl  = (const float*)d_in[9];
    const float* bl  = (const float*)d_in[10];
    float* out = (float*)d_out;

    char* ws_base = (char*)d_ws;
    size_t off = 0;
    auto alloc = [&](size_t bytes) -> char* {
        char* p = ws_base + off;
        off = (off + bytes + 255) & ~(size_t)255;
        return p;
    };
    unsigned short* hb      = (unsigned short*)alloc((size_t)NN * HIDD * 2);
    unsigned short* gb      = (unsigned short*)alloc((size_t)NN * FD * 2);
    float*          asrcP   = (float*)alloc((size_t)NN * 8 * 4);
    float*          adstP   = (float*)alloc((size_t)NN * 8 * 4);
    unsigned int*   counts  = (unsigned int*)alloc((size_t)NN * 4);
    unsigned int*   offsets = (unsigned int*)alloc((size_t)(NN + 1) * 4);
    unsigned int*   cursor  = (unsigned int*)alloc((size_t)NN * 4);
    unsigned int*   flag    = (unsigned int*)alloc(256);
    unsigned int*   bsum    = (unsigned int*)alloc((size_t)256 * 4);
    uint4*          edata   = (uint4*)alloc((size_t)E2T * 16);
    unsigned short* Wt      = (unsigned short*)alloc((size_t)64 * CURD * 2);
    unsigned short* Wgt     = (unsigned short*)alloc((size_t)6 * 64 * 64 * 2);
    unsigned short* Wlt     = (unsigned short*)alloc((size_t)64 * CATK * 2);
    float*          wsv     = (float*)alloc((size_t)6 * 64 * 4);
    float*          wdv     = (float*)alloc((size_t)6 * 64 * 4);
    if (off > ws_size) return;

    const int nb64 = (NN + 63) / 64;    // 782
    const int nbw  = (NN + 3) / 4;      // 12500
    const int nbs  = (NN + 255) / 256;  // 196

    hipLaunchKernelGGL(k_setup, dim3(B_TOT), dim3(256), 0, stream,
                       ei, Wp, Wl, Wg, ats, atd, counts, cursor, flag, Wt, Wlt, Wgt, wsv, wdv);
    hipLaunchKernelGGL(k_pre,   dim3(nb64), dim3(256), 0, stream, x, Wt, bp, hb);
    hipLaunchKernelGGL(k_att,   dim3(nbw), dim3(256), 0, stream, hb, wsv, wdv, asrcP, adstP);
    hipLaunchKernelGGL(k_hist,  dim3((EE + 255) / 256), dim3(256), 0, stream, ei, flag, counts);
    hipLaunchKernelGGL(k_bsum,  dim3(nbs), dim3(256), 0, stream, counts, bsum);
    hipLaunchKernelGGL(k_off,   dim3(nbs), dim3(256), 0, stream, counts, bsum, offsets);
    hipLaunchKernelGGL(k_fill,  dim3((E2T + 255) / 256), dim3(256), 0, stream,
                       ei, flag, offsets, cursor, asrcP, adstP, edata);
    hipLaunchKernelGGL(k_agg,   dim3(nbw), dim3(256), 0, stream, offsets, edata, hb, gb);
    hipLaunchKernelGGL(k_tail,  dim3(nb64), dim3(256), 0, stream, gb, hb, Wgt, bg, Wlt, bl, out);
}

// Round 15
// 180.267 us; speedup vs baseline: 1.6515x; 1.1631x over previous
//
#include <hip/hip_runtime.h>
#include <hip/hip_bf16.h>

// GNN forward: pre-Linear -> GATConv(6 heads, self-loops, edge softmax) -> concat -> Linear
// - Aggregation identity: sum_e coef_e*(h[s]@Wg) = (sum_e coef_e*h[s])@Wg -> gather 128B bf16 rows
// - a_src/a_dst computed as k_pre REGISTER EPILOGUE (f32 acc + shfl-reduce; no extra MFMA cols,
//   no LDS changes — distinct from the banned R6/R7 80-col B-tile fusion)
// - Self-loops handled inline in k_agg (edata/CSR hold only the EE real edges)
// - Per-edge softmax weights computed once in k_fill -> 16B f16 records {src, 6 x f16 w}
// - k_agg: readfirstlane scalar record loads, 8-edge unroll
// - k_tail: separate BsG/BsL LDS buffers -> 3 barriers/head
// - R12/R13 lesson: launch-fusion bundles (hist-in-setup, single-block scan) were net NEGATIVE.
// N=50000, E=800000, CUR=512, HID=64, OUT=64, HEADS=6

#define NN    50000
#define EE    800000
#define CURD  512
#define HIDD  64
#define FD    384        // HEADS*OUT
#define CATK  448        // HID + FD

typedef __attribute__((ext_vector_type(8))) short short8;
typedef __attribute__((ext_vector_type(4))) float f32x4;

static __device__ __forceinline__ float b2f(unsigned short u) {
    union { unsigned int i; float f; } x; x.i = ((unsigned int)u) << 16; return x.f;
}
static __device__ __forceinline__ unsigned short f2b(float f) {
    unsigned int x = __float_as_uint(f);
    unsigned int r = (x + 0x7fffu + ((x >> 16) & 1u)) >> 16;
    return (unsigned short)r;
}
static __device__ __forceinline__ unsigned int packbf(float a, float b) {
    return (unsigned int)f2b(a) | ((unsigned int)f2b(b) << 16);
}
static __device__ __forceinline__ unsigned short f2h(float f) {
    _Float16 h = (_Float16)f; unsigned short u; __builtin_memcpy(&u, &h, 2); return u;
}
static __device__ __forceinline__ float h2f(unsigned short u) {
    _Float16 h; __builtin_memcpy(&h, &u, 2); return (float)h;
}
static __device__ __forceinline__ float lrelu(float v, float a) { return v > 0.f ? v : a * v; }

// ---------------- k_setup: init + detect + 3 weight transposes + watt(+bias proj) ----------
#define B_INIT 196
#define B_DET  196
#define B_TRWP 197            // 128 blocks: Wt[c][k]=Wp[k][c]
#define B_TRWL 325            // 112 blocks: Wlt[c][k]=Wl[k][c]
#define B_TRWG 437            // 96 blocks:  Wgt[h][c][k]=Wg[k][h*64+c]
#define B_WATT 533            // 2 blocks:   wsv/wdv[h][k] + bws/bwd[h]
#define B_TOT  535

__global__ void k_setup(const int* __restrict__ ei,
                        const float* __restrict__ Wp, const float* __restrict__ bp,
                        const float* __restrict__ Wl, const float* __restrict__ Wg,
                        const float* __restrict__ atts, const float* __restrict__ attd,
                        unsigned int* __restrict__ counts, unsigned int* __restrict__ cursor,
                        unsigned int* __restrict__ flag,
                        unsigned short* __restrict__ Wt, unsigned short* __restrict__ Wlt,
                        unsigned short* __restrict__ Wgt,
                        float* __restrict__ wsv, float* __restrict__ wdv,
                        float* __restrict__ bws, float* __restrict__ bwd) {
    __shared__ unsigned int anyv;
    const int b = blockIdx.x, t = threadIdx.x;
    if (b < B_INIT) {
        int i = b * 256 + t;
        if (i < NN) { counts[i] = 0u; cursor[i] = 0u; }
    } else if (b == B_DET) {
        if (t == 0) anyv = 0u;
        __syncthreads();
        unsigned int v = 0;
        for (int i = t; i < 2048; i += 256) v |= (unsigned int)ei[2 * i + 1];
        atomicOr(&anyv, v);
        __syncthreads();
        if (t == 0) *flag = (anyv == 0u) ? 1u : 0u;   // 1 => int64 layout
    } else if (b < B_TRWL) {
        int i = (b - B_TRWP) * 256 + t;               // Wt[c][k]=Wp[k][c], K=512
        int c = i >> 9, k = i & 511;
        Wt[i] = f2b(Wp[k * 64 + c]);
    } else if (b < B_TRWG) {
        int i = (b - B_TRWL) * 256 + t;
        if (i < 64 * CATK) {
            int c = i / CATK, k = i - c * CATK;
            Wlt[i] = f2b(Wl[k * 64 + c]);
        }
    } else if (b < B_WATT) {
        int i = (b - B_TRWG) * 256 + t;
        int hd = i >> 12, rem = i & 4095, c = rem >> 6, k = rem & 63;
        Wgt[i] = f2b(Wg[k * FD + hd * 64 + c]);
    } else {
        int j = (b - B_WATT) * 256 + t;               // 384 total; whole waves valid/invalid
        if (j < 384) {
            int hd = j >> 6, k = j & 63;
            float s = 0.f, d = 0.f;
            for (int c = 0; c < 64; c++) {
                float w = Wg[k * FD + hd * 64 + c];
                s = fmaf(w, atts[hd * 64 + c], s);
                d = fmaf(w, attd[hd * 64 + c], d);
            }
            wsv[j] = s; wdv[j] = d;
            // bias projections: bws[hd] = sum_k bp[k]*wsv[hd][k] (wave = one head)
            float pbs = bp[k] * s, pbd = bp[k] * d;
            #pragma unroll
            for (int o = 32; o > 0; o >>= 1) {
                pbs += __shfl_xor(pbs, o, 64);
                pbd += __shfl_xor(pbd, o, 64);
            }
            if ((t & 63) == 0) { bws[hd] = pbs; bwd[hd] = pbd; }
        }
    }
}

// ---- K1: hb = bf16(x @ W_pre + b_pre); epilogue computes asrcP/adstP from f32 acc ----
__global__ __launch_bounds__(256) void k_pre(const float* __restrict__ x,
                                             const unsigned short* __restrict__ Wt,
                                             const float* __restrict__ bp,
                                             const float* __restrict__ wsv,
                                             const float* __restrict__ wdv,
                                             const float* __restrict__ bws,
                                             const float* __restrict__ bwd,
                                             unsigned short* __restrict__ hb,
                                             float* __restrict__ asrcP, float* __restrict__ adstP) {
    __shared__ unsigned short As[64][72];
    __shared__ unsigned short Bs[64][72];
    const int t  = threadIdx.x;
    const int n0 = blockIdx.x * 64;
    const int w = t >> 6, l = t & 63;
    const int fr = l & 15, fq = l >> 4;
    const int ar = t >> 2, ac = (t & 3) * 16;
    int arg = n0 + ar; if (arg >= NN) arg = NN - 1;
    f32x4 acc[4];
    #pragma unroll
    for (int nb = 0; nb < 4; nb++) acc[nb] = (f32x4){0.f, 0.f, 0.f, 0.f};

    for (int kt = 0; kt < CURD; kt += 64) {
        const float4* xp = (const float4*)(x + (size_t)arg * CURD + kt + ac);
        float4 a0 = xp[0], a1 = xp[1], a2 = xp[2], a3 = xp[3];
        const uint4* wp = (const uint4*)(Wt + (size_t)ar * CURD + kt + ac);
        uint4 b0 = wp[0], b1 = wp[1];
        __syncthreads();
        *(uint4*)&As[ar][ac]     = make_uint4(packbf(a0.x,a0.y), packbf(a0.z,a0.w),
                                              packbf(a1.x,a1.y), packbf(a1.z,a1.w));
        *(uint4*)&As[ar][ac + 8] = make_uint4(packbf(a2.x,a2.y), packbf(a2.z,a2.w),
                                              packbf(a3.x,a3.y), packbf(a3.z,a3.w));
        *(uint4*)&Bs[ar][ac]     = b0;
        *(uint4*)&Bs[ar][ac + 8] = b1;
        __syncthreads();
        #pragma unroll
        for (int ks = 0; ks < 2; ks++) {
            short8 af = *(const short8*)&As[w * 16 + fr][ks * 32 + fq * 8];
            #pragma unroll
            for (int nb = 0; nb < 4; nb++) {
                short8 bf = *(const short8*)&Bs[nb * 16 + fr][ks * 32 + fq * 8];
                acc[nb] = __builtin_amdgcn_mfma_f32_16x16x32_bf16(af, bf, acc[nb], 0, 0, 0);
            }
        }
    }
    #pragma unroll
    for (int nb = 0; nb < 4; nb++) {
        const int col = nb * 16 + fr;
        const float bias = bp[col];
        #pragma unroll
        for (int r = 0; r < 4; r++) {
            const int row = n0 + w * 16 + fq * 4 + r;
            if (row < NN) hb[(size_t)row * HIDD + col] = f2b(acc[nb][r] + bias);
        }
    }
    // attention-logit epilogue: asrc[row][hd] = sum_col acc[row][col]*wsv[hd][col] + bws[hd]
    // lane holds cols nb*16+fr for rows w*16+fq*4+r; reduce over the 16 fr-lanes (same fq group)
    for (int hd = 0; hd < 6; hd++) {
        float wsl[4], wdl[4];
        #pragma unroll
        for (int nb = 0; nb < 4; nb++) {
            wsl[nb] = wsv[hd * 64 + nb * 16 + fr];
            wdl[nb] = wdv[hd * 64 + nb * 16 + fr];
        }
        float ps[4], pd[4];
        #pragma unroll
        for (int r = 0; r < 4; r++) {
            ps[r] = acc[0][r] * wsl[0];
            pd[r] = acc[0][r] * wdl[0];
            #pragma unroll
            for (int nb = 1; nb < 4; nb++) {
                ps[r] = fmaf(acc[nb][r], wsl[nb], ps[r]);
                pd[r] = fmaf(acc[nb][r], wdl[nb], pd[r]);
            }
        }
        #pragma unroll
        for (int o = 1; o < 16; o <<= 1) {
            #pragma unroll
            for (int r = 0; r < 4; r++) {
                ps[r] += __shfl_xor(ps[r], o, 64);
                pd[r] += __shfl_xor(pd[r], o, 64);
            }
        }
        if (fr == 0) {
            const float bs = bws[hd], bd = bwd[hd];
            #pragma unroll
            for (int r = 0; r < 4; r++) {
                const int row = n0 + w * 16 + fq * 4 + r;
                if (row < NN) {
                    asrcP[(size_t)row * 8 + hd] = ps[r] + bs;
                    adstP[(size_t)row * 8 + hd] = pd[r] + bd;
                }
            }
        }
    }
}

// ---------------- in-degree histogram (real edges only) ----------------
__global__ void k_hist(const int* __restrict__ ei, const unsigned int* __restrict__ flag,
                       unsigned int* __restrict__ counts) {
    int e = blockIdx.x * 256 + threadIdx.x;
    if (e >= EE) return;
    const bool wide = (*flag != 0u);
    int d = wide ? ei[2 * (EE + e)] : ei[EE + e];
    atomicAdd(&counts[d], 1u);
}

// ---------------- scan phase 1: per-block sums ----------------
__global__ __launch_bounds__(256) void k_bsum(const unsigned int* __restrict__ counts,
                                              unsigned int* __restrict__ bsum) {
    __shared__ unsigned int wt[4];
    const int t = threadIdx.x, w = t >> 6, l = t & 63;
    int i = blockIdx.x * 256 + t;
    unsigned int v = (i < NN) ? counts[i] : 0u;
    #pragma unroll
    for (int o = 32; o > 0; o >>= 1) v += __shfl_xor(v, o, 64);
    if (l == 0) wt[w] = v;
    __syncthreads();
    if (t == 0) bsum[blockIdx.x] = wt[0] + wt[1] + wt[2] + wt[3];
}

// ---------------- scan phase 2: offsets (inline redundant scan of 196 block sums) ----------------
__global__ __launch_bounds__(256) void k_off(const unsigned int* __restrict__ counts,
                                             const unsigned int* __restrict__ bsum,
                                             unsigned int* __restrict__ offsets) {
    __shared__ unsigned int sc[256];
    __shared__ unsigned int wt[4];
    const int t = threadIdx.x, w = t >> 6, l = t & 63;
    const int nb = (NN + 255) / 256;   // 196
    unsigned int bv = (t < nb) ? bsum[t] : 0u;
    sc[t] = bv;
    __syncthreads();
    for (int o = 1; o < 256; o <<= 1) {
        unsigned int xv = (t >= o) ? sc[t - o] : 0u;
        __syncthreads();
        sc[t] += xv;
        __syncthreads();
    }
    const unsigned int bpre = sc[blockIdx.x] -
        ((blockIdx.x < nb) ? bsum[blockIdx.x] : 0u);   // exclusive prefix for this block

    int i = blockIdx.x * 256 + t;
    unsigned int v = (i < NN) ? counts[i] : 0u;
    unsigned int incl = v;
    #pragma unroll
    for (int o = 1; o < 64; o <<= 1) {
        unsigned int xv = __shfl_up(incl, o, 64);
        if (l >= o) incl += xv;
    }
    if (l == 63) wt[w] = incl;
    __syncthreads();
    unsigned int woff = 0;
    #pragma unroll
    for (int ww = 0; ww < 4; ww++) woff += (ww < w) ? wt[ww] : 0u;
    const unsigned int base = bpre + woff;
    if (i < NN) offsets[i] = base + incl - v;
    if (i == NN - 1) offsets[NN] = base + incl;
}

// ---------------- CSR fill + per-edge weights: edata[pos] = {src, 6 x f16 w} (16B) ----------------
__global__ void k_fill(const int* __restrict__ ei, const unsigned int* __restrict__ flag,
                       const unsigned int* __restrict__ offsets, unsigned int* __restrict__ cursor,
                       const float* __restrict__ asrcP, const float* __restrict__ adstP,
                       uint4* __restrict__ edata) {
    int e = blockIdx.x * 256 + threadIdx.x;
    if (e >= EE) return;
    const bool wide = (*flag != 0u);
    const int s = wide ? ei[2 * e] : ei[e];
    const int d = wide ? ei[2 * (EE + e)] : ei[EE + e];
    unsigned int pos = offsets[d] + atomicAdd(&cursor[d], 1u);
    const float4 s0 = *(const float4*)(asrcP + (size_t)s * 8);
    const float2 s1 = *(const float2*)(asrcP + (size_t)s * 8 + 4);
    const float4 d0 = *(const float4*)(adstP + (size_t)d * 8);
    const float2 d1 = *(const float2*)(adstP + (size_t)d * 8 + 4);
    const float as[6] = {s0.x, s0.y, s0.z, s0.w, s1.x, s1.y};
    const float ad[6] = {d0.x, d0.y, d0.z, d0.w, d1.x, d1.y};
    unsigned short wh[6];
    #pragma unroll
    for (int hd = 0; hd < 6; hd++) {
        float a = as[hd] + ad[hd];
        a = fmaxf(a, 0.2f * a);                 // leaky_relu 0.2
        wh[hd] = f2h(__expf(a));                // shift skipped: alpha O(1), softmax shift-invariant
    }
    uint4 u;
    u.x = (unsigned int)s;
    u.y = (unsigned int)wh[0] | ((unsigned int)wh[1] << 16);
    u.z = (unsigned int)wh[2] | ((unsigned int)wh[3] << 16);
    u.w = (unsigned int)wh[4] | ((unsigned int)wh[5] << 16);
    edata[pos] = u;
}

// ---- k_agg: self-loop inline + scalar f16-record loads (8-edge unroll) + row gather ----
#define W6H(u, nm) \
    const float nm[6] = {h2f(u.y & 0xffff), h2f(u.y >> 16), h2f(u.z & 0xffff), \
                         h2f(u.z >> 16),    h2f(u.w & 0xffff), h2f(u.w >> 16)};

__global__ __launch_bounds__(256) void k_agg(const unsigned int* __restrict__ offsets,
                                             const uint4* __restrict__ edata,
                                             const float* __restrict__ asrcP,
                                             const float* __restrict__ adstP,
                                             const unsigned short* __restrict__ hb,
                                             unsigned short* __restrict__ gb) {
    const int n = blockIdx.x * 4 + (threadIdx.x >> 6);  // one wave per node
    if (n >= NN) return;
    const int l = threadIdx.x & 63;
    const unsigned int e0 = __builtin_amdgcn_readfirstlane(offsets[n]);
    const unsigned int e1 = __builtin_amdgcn_readfirstlane(offsets[n + 1]);
    float acc[6], den[6];
    {   // self loop: w = exp(lrelu(asrc[n]+adst[n])), contribution w*hb[n]
        const float4 a0 = *(const float4*)(asrcP + (size_t)n * 8);
        const float2 a1 = *(const float2*)(asrcP + (size_t)n * 8 + 4);
        const float4 d0 = *(const float4*)(adstP + (size_t)n * 8);
        const float2 d1 = *(const float2*)(adstP + (size_t)n * 8 + 4);
        const float as[6] = {a0.x, a0.y, a0.z, a0.w, a1.x, a1.y};
        const float ad[6] = {d0.x, d0.y, d0.z, d0.w, d1.x, d1.y};
        const float hvn = b2f(hb[(size_t)n * HIDD + l]);
        #pragma unroll
        for (int hd = 0; hd < 6; hd++) {
            float a = as[hd] + ad[hd];
            a = fmaxf(a, 0.2f * a);
            const float wv = __expf(a);
            acc[hd] = wv * hvn;
            den[hd] = wv;
        }
    }

    unsigned int e = e0;
    for (; e + 8 <= e1; e += 8) {
        const unsigned int eu = __builtin_amdgcn_readfirstlane(e);  // uniform -> s_load records
        uint4 r[8];
        #pragma unroll
        for (int j = 0; j < 8; j++) r[j] = edata[(size_t)eu + j];
        float hv[8];
        #pragma unroll
        for (int j = 0; j < 8; j++) hv[j] = b2f(hb[(size_t)r[j].x * HIDD + l]);
        #pragma unroll
        for (int j = 0; j < 8; j++) {
            W6H(r[j], wj)
            #pragma unroll
            for (int hd = 0; hd < 6; hd++) {
                acc[hd] = fmaf(wj[hd], hv[j], acc[hd]);
                den[hd] += wj[hd];
            }
        }
    }
    for (; e + 4 <= e1; e += 4) {
        const unsigned int eu = __builtin_amdgcn_readfirstlane(e);
        uint4 r[4];
        #pragma unroll
        for (int j = 0; j < 4; j++) r[j] = edata[(size_t)eu + j];
        float hv[4];
        #pragma unroll
        for (int j = 0; j < 4; j++) hv[j] = b2f(hb[(size_t)r[j].x * HIDD + l]);
        #pragma unroll
        for (int j = 0; j < 4; j++) {
            W6H(r[j], wj)
            #pragma unroll
            for (int hd = 0; hd < 6; hd++) {
                acc[hd] = fmaf(wj[hd], hv[j], acc[hd]);
                den[hd] += wj[hd];
            }
        }
    }
    for (; e < e1; e++) {
        const unsigned int eu = __builtin_amdgcn_readfirstlane(e);
        const uint4 u = edata[(size_t)eu];
        const float hv = b2f(hb[(size_t)u.x * HIDD + l]);
        W6H(u, wv)
        #pragma unroll
        for (int hd = 0; hd < 6; hd++) {
            acc[hd] = fmaf(wv[hd], hv, acc[hd]);
            den[hd] += wv[hd];
        }
    }
    #pragma unroll
    for (int hd = 0; hd < 6; hd++)
        gb[(size_t)n * FD + hd * 64 + l] = f2b(acc[hd] / den[hd]);
}

// ---- k_tail: out = [hb | lrelu(gb@blockdiag(Wg)+bg)] @ W_lin + b_lin  (3 barriers/head) ----
__global__ __launch_bounds__(256) void k_tail(const unsigned short* __restrict__ gb,
                                              const unsigned short* __restrict__ hb,
                                              const unsigned short* __restrict__ Wgt,
                                              const float* __restrict__ bg,
                                              const unsigned short* __restrict__ Wlt,  // [64][448]
                                              const float* __restrict__ bl,
                                              float* __restrict__ out) {
    __shared__ unsigned short As[64][72];   // A operand (hb, then gb head tiles)
    __shared__ unsigned short BsG[64][72];  // gat2 B (Wgt[hd])
    __shared__ unsigned short BsL[64][72];  // fin  B (Wlt block)
    __shared__ unsigned short Ct[64][72];   // gat2 output staging
    const int t  = threadIdx.x;
    const int n0 = blockIdx.x * 64;
    const int w = t >> 6, l = t & 63;
    const int fr = l & 15, fq = l >> 4;
    const int ar = t >> 2, ac = (t & 3) * 16;
    int arg = n0 + ar; if (arg >= NN) arg = NN - 1;

    f32x4 oacc[4];
    #pragma unroll
    for (int nb = 0; nb < 4; nb++) oacc[nb] = (f32x4){0.f, 0.f, 0.f, 0.f};

    {   // kt = 0: A = hb tile, B = Wlt[:, 0:64]
        const uint4* hp = (const uint4*)(hb + (size_t)arg * HIDD + ac);
        uint4 aA = hp[0], aB = hp[1];
        const uint4* wp = (const uint4*)(Wlt + (size_t)ar * CATK + 0 + ac);
        uint4 b0 = wp[0], b1 = wp[1];
        *(uint4*)&As[ar][ac]      = aA;
        *(uint4*)&As[ar][ac + 8]  = aB;
        *(uint4*)&BsL[ar][ac]     = b0;
        *(uint4*)&BsL[ar][ac + 8] = b1;
        __syncthreads();
        #pragma unroll
        for (int ks = 0; ks < 2; ks++) {
            short8 af = *(const short8*)&As[w * 16 + fr][ks * 32 + fq * 8];
            #pragma unroll
            for (int nb = 0; nb < 4; nb++) {
                short8 bf = *(const short8*)&BsL[nb * 16 + fr][ks * 32 + fq * 8];
                oacc[nb] = __builtin_amdgcn_mfma_f32_16x16x32_bf16(af, bf, oacc[nb], 0, 0, 0);
            }
        }
    }

    for (int hd = 0; hd < 6; hd++) {
        __syncthreads();   // previous iter's MFMA reads (As/BsG/BsL/Ct) complete
        {   // stage A = gb tile (head hd), BsG = Wgt[hd], BsL = Wlt[:, 64+hd*64 ..]
            const uint4* gp = (const uint4*)(gb + (size_t)arg * FD + hd * 64 + ac);
            uint4 aA = gp[0], aB = gp[1];
            const uint4* wpg = (const uint4*)(Wgt + (size_t)hd * 4096 + ar * 64 + ac);
            uint4 g0 = wpg[0], g1 = wpg[1];
            const uint4* wpl = (const uint4*)(Wlt + (size_t)ar * CATK + 64 + hd * 64 + ac);
            uint4 l0 = wpl[0], l1 = wpl[1];
            *(uint4*)&As[ar][ac]      = aA;
            *(uint4*)&As[ar][ac + 8]  = aB;
            *(uint4*)&BsG[ar][ac]     = g0;
            *(uint4*)&BsG[ar][ac + 8] = g1;
            *(uint4*)&BsL[ar][ac]     = l0;
            *(uint4*)&BsL[ar][ac + 8] = l1;
        }
        __syncthreads();
        f32x4 acc2[4];
        #pragma unroll
        for (int nb = 0; nb < 4; nb++) acc2[nb] = (f32x4){0.f, 0.f, 0.f, 0.f};
        #pragma unroll
        for (int ks = 0; ks < 2; ks++) {
            short8 af = *(const short8*)&As[w * 16 + fr][ks * 32 + fq * 8];
            #pragma unroll
            for (int nb = 0; nb < 4; nb++) {
                short8 bf = *(const short8*)&BsG[nb * 16 + fr][ks * 32 + fq * 8];
                acc2[nb] = __builtin_amdgcn_mfma_f32_16x16x32_bf16(af, bf, acc2[nb], 0, 0, 0);
            }
        }
        #pragma unroll
        for (int nb = 0; nb < 4; nb++) {
            const int col = nb * 16 + fr;
            const float bias = bg[hd * 64 + col];
            #pragma unroll
            for (int r = 0; r < 4; r++)
                Ct[w * 16 + fq * 4 + r][col] = f2b(lrelu(acc2[nb][r] + bias, 0.01f));
        }
        __syncthreads();   // all Ct writes visible
        #pragma unroll
        for (int ks = 0; ks < 2; ks++) {
            short8 af = *(const short8*)&Ct[w * 16 + fr][ks * 32 + fq * 8];
            #pragma unroll
            for (int nb = 0; nb < 4; nb++) {
                short8 bf = *(const short8*)&BsL[nb * 16 + fr][ks * 32 + fq * 8];
                oacc[nb] = __builtin_amdgcn_mfma_f32_16x16x32_bf16(af, bf, oacc[nb], 0, 0, 0);
            }
        }
    }

    #pragma unroll
    for (int nb = 0; nb < 4; nb++) {
        const int col = nb * 16 + fr;
        const float bias = bl[col];
        #pragma unroll
        for (int r = 0; r < 4; r++) {
            const int row = n0 + w * 16 + fq * 4 + r;
            if (row < NN) out[(size_t)row * HIDD + col] = oacc[nb][r] + bias;
        }
    }
}

extern "C" void kernel_launch(void* const* d_in, const int* in_sizes, int n_in,
                              void* d_out, int out_size, void* d_ws, size_t ws_size,
                              hipStream_t stream) {
    const float* x   = (const float*)d_in[0];
    const int*   ei  = (const int*)d_in[1];
    // d_in[2] edge_weight: unused by the reference forward
    const float* Wp  = (const float*)d_in[3];
    const float* bp  = (const float*)d_in[4];
    const float* Wg  = (const float*)d_in[5];
    const float* ats = (const float*)d_in[6];
    const float* atd = (const float*)d_in[7];
    const float* bg  = (const float*)d_in[8];
    const float* Wl  = (const float*)d_in[9];
    const float* bl  = (const float*)d_in[10];
    float* out = (float*)d_out;

    char* ws_base = (char*)d_ws;
    size_t off = 0;
    auto alloc = [&](size_t bytes) -> char* {
        char* p = ws_base + off;
        off = (off + bytes + 255) & ~(size_t)255;
        return p;
    };
    unsigned short* hb      = (unsigned short*)alloc((size_t)NN * HIDD * 2);
    unsigned short* gb      = (unsigned short*)alloc((size_t)NN * FD * 2);
    float*          asrcP   = (float*)alloc((size_t)NN * 8 * 4);
    float*          adstP   = (float*)alloc((size_t)NN * 8 * 4);
    unsigned int*   counts  = (unsigned int*)alloc((size_t)NN * 4);
    unsigned int*   offsets = (unsigned int*)alloc((size_t)(NN + 1) * 4);
    unsigned int*   cursor  = (unsigned int*)alloc((size_t)NN * 4);
    unsigned int*   flag    = (unsigned int*)alloc(256);
    unsigned int*   bsum    = (unsigned int*)alloc((size_t)256 * 4);
    uint4*          edata   = (uint4*)alloc((size_t)EE * 16);
    unsigned short* Wt      = (unsigned short*)alloc((size_t)64 * CURD * 2);
    unsigned short* Wgt     = (unsigned short*)alloc((size_t)6 * 64 * 64 * 2);
    unsigned short* Wlt     = (unsigned short*)alloc((size_t)64 * CATK * 2);
    float*          wsv     = (float*)alloc((size_t)6 * 64 * 4);
    float*          wdv     = (float*)alloc((size_t)6 * 64 * 4);
    float*          bws     = (float*)alloc((size_t)8 * 4);
    float*          bwd     = (float*)alloc((size_t)8 * 4);
    if (off > ws_size) return;

    const int nb64 = (NN + 63) / 64;    // 782
    const int nbw  = (NN + 3) / 4;      // 12500
    const int nbs  = (NN + 255) / 256;  // 196

    hipLaunchKernelGGL(k_setup, dim3(B_TOT), dim3(256), 0, stream,
                       ei, Wp, bp, Wl, Wg, ats, atd, counts, cursor, flag,
                       Wt, Wlt, Wgt, wsv, wdv, bws, bwd);
    hipLaunchKernelGGL(k_pre,   dim3(nb64), dim3(256), 0, stream,
                       x, Wt, bp, wsv, wdv, bws, bwd, hb, asrcP, adstP);
    hipLaunchKernelGGL(k_hist,  dim3((EE + 255) / 256), dim3(256), 0, stream, ei, flag, counts);
    hipLaunchKernelGGL(k_bsum,  dim3(nbs), dim3(256), 0, stream, counts, bsum);
    hipLaunchKernelGGL(k_off,   dim3(nbs), dim3(256), 0, stream, counts, bsum, offsets);
    hipLaunchKernelGGL(k_fill,  dim3((EE + 255) / 256), dim3(256), 0, stream,
                       ei, flag, offsets, cursor, asrcP, adstP, edata);
    hipLaunchKernelGGL(k_agg,   dim3(nbw), dim3(256), 0, stream,
                       offsets, edata, asrcP, adstP, hb, gb);
    hipLaunchKernelGGL(k_tail,  dim3(nb64), dim3(256), 0, stream, gb, hb, Wgt, bg, Wlt, bl, out);
}